// Round 7
// baseline (384.025 us; speedup 1.0000x reference)
//
#include <hip/hip_runtime.h>

typedef unsigned short u16;
typedef __attribute__((ext_vector_type(8))) __bf16 bf16x8;
typedef __attribute__((ext_vector_type(4))) float f32x4;

#define NF    39
#define NNUM  13
#define NCAT  26
#define VOC   100000
#define NPAIR 741
#define KHID  23712   /* 2*741*16 */
#define BATCH 4096
#define HD1   1024
#define HD2   512
#define HD3   256

__device__ __forceinline__ u16 f2bf(float f) {
  unsigned u = __builtin_bit_cast(unsigned, f);
  return (u16)((u + 0x7fffu + ((u >> 16) & 1u)) >> 16);   // RNE
}

__device__ __forceinline__ void gload16(const void* g, void* l) {
  __builtin_amdgcn_global_load_lds((const __attribute__((address_space(1))) void*)g,
                                   (__attribute__((address_space(3))) void*)l, 16, 0, 0);
}

// ---------------------------------------------------------------------------
// Front end: gather + SE + bilinear proj + pairwise products -> hid bf16 [B][23712]
// ---------------------------------------------------------------------------
__global__ __launch_bounds__(256) void fuse_front(
    const int* __restrict__ cat, const float* __restrict__ num,
    const float* __restrict__ tables, const float* __restrict__ nemb,
    const float* __restrict__ Wse1, const float* __restrict__ Wse2,
    const float* __restrict__ Wbil, u16* __restrict__ hid)
{
  __shared__ float xs[NF][16];
  __shared__ float wb[NF][16][16];   // [f][e][d]
  __shared__ float pr[NF][16];       // proj
  __shared__ float Zs[NF], Ts[NNUM], As[NF];
  __shared__ unsigned char pis[NPAIR], pjs[NPAIR];

  const int b = blockIdx.x;
  const int tid = threadIdx.x;

  for (int i = tid; i < NF * 256; i += 256) ((float*)wb)[i] = Wbil[i];

  for (int t = tid; t < NNUM * 16; t += 256) {
    int f = t >> 4, e = t & 15;
    xs[f][e] = num[b * NNUM + f] * nemb[t];
  }
  for (int t = tid; t < NCAT * 16; t += 256) {
    int c = t >> 4, e = t & 15;
    int cv = cat[b * NCAT + c];
    xs[NNUM + c][e] = tables[((size_t)c * VOC + cv) * 16 + e];
  }
  for (int p = tid; p < NPAIR; p += 256) {
    int i = 0, rs = 0;
    while (p >= rs + (NF - 1 - i)) { rs += NF - 1 - i; ++i; }
    pis[p] = (unsigned char)i;
    pjs[p] = (unsigned char)(i + 1 + (p - rs));
  }
  __syncthreads();

  if (tid < NF) {
    float s = 0.f;
    #pragma unroll
    for (int e = 0; e < 16; ++e) s += xs[tid][e];
    Zs[tid] = s * (1.f / 16.f);
  }
  __syncthreads();
  if (tid < NNUM) {
    float s = 0.f;
    for (int f = 0; f < NF; ++f) s += Zs[f] * Wse1[f * NNUM + tid];
    Ts[tid] = fmaxf(s, 0.f);
  }
  __syncthreads();
  if (tid < NF) {
    float s = 0.f;
    for (int r = 0; r < NNUM; ++r) s += Ts[r] * Wse2[r * NF + tid];
    As[tid] = fmaxf(s, 0.f);
  }
  for (int t = tid; t < NF * 16; t += 256) {
    int f = t >> 4, d = t & 15;
    float s = 0.f;
    #pragma unroll
    for (int e = 0; e < 16; ++e) s += xs[f][e] * wb[f][e][d];
    pr[f][d] = s;
  }
  __syncthreads();

  u16* hr = hid + (size_t)b * KHID;
  for (int idx = tid; idx < NPAIR * 16; idx += 256) {
    int p = idx >> 4, e = idx & 15;
    int i = pis[p], j = pjs[p];
    float bv = pr[i][e] * xs[j][e];
    hr[NPAIR * 16 + idx] = f2bf(bv);
    hr[idx] = f2bf(As[i] * As[j] * bv);
  }
}

// ---------------------------------------------------------------------------
// Transpose + cast: in f32 [K][N] -> out bf16 [N][K]
// ---------------------------------------------------------------------------
__global__ __launch_bounds__(256) void transpose_cast(
    const float* __restrict__ in, u16* __restrict__ out, int K, int N)
{
  __shared__ float t[32][33];
  const int k0 = blockIdx.x * 32, n0 = blockIdx.y * 32;
  const int c = threadIdx.x & 31, r = threadIdx.x >> 5;
  #pragma unroll
  for (int it = 0; it < 4; ++it)
    t[r + it * 8][c] = in[(size_t)(k0 + r + it * 8) * N + n0 + c];
  __syncthreads();
  #pragma unroll
  for (int it = 0; it < 4; ++it)
    out[(size_t)(n0 + r + it * 8) * K + k0 + c] = f2bf(t[c][r + it * 8]);
}

// ---------------------------------------------------------------------------
// 256x256 8-wave pipelined bf16 GEMM. 2D-grouped XCD swizzle + T2 LDS swizzle
// + T3/T4 counted vmcnt 4-slot ring + T5 setprio + intra-phase read/MFMA
// software pipeline: bg[0..3],af[0..1] up front, then 8 segments of
// {read af[m+2] | 4xMFMA} pinned by sched_barrier(0) so LDS reads drain
// under the MFMA stream instead of serializing ahead of it.
// Slot-reuse proof unchanged from round 5/6: all reads of slot t&3 complete
// before the wave's last MFMA of phase t -> before phase t+1's entry barrier,
// which precedes staging into slot (t+4)&3 == t&3.
// ---------------------------------------------------------------------------
__global__ __launch_bounds__(512, 2) void gemm8_bf16(
    const u16* __restrict__ A, const u16* __restrict__ Bt,
    float* __restrict__ Cp, int M, int N, int K, int totku, int kpb)
{
  __shared__ __align__(16) u16 lds[4 * 16384];   // 128 KiB

  const int tid = threadIdx.x;
  const int wid = tid >> 6, lane = tid & 63;

  // 2D-grouped bijective XCD swizzle (assumes dispatch d -> XCD d%8):
  // XCD x owns mb in {4*(x&3)..+3}, sb in {2*(x>>2), 2*(x>>2)+1}, all nb.
  const int d = blockIdx.x;
  const int x = d & 7;                         // XCD
  const int j = d >> 3;                        // [0,32)
  const int mb = ((x & 3) << 2) | (j & 3);     // [0,16)
  const int nb = (j >> 2) & 3;                 // [0,4)
  const int sb = ((x >> 2) << 1) | (j >> 4);   // [0,4)

  const int ks0 = sb * kpb;
  const int kunits = (totku - ks0 < kpb) ? (totku - ks0) : kpb;

  const int wm = wid >> 2, wn = wid & 3;        // 2M x 4N waves
  const int lrow = lane & 15, c0 = lane >> 4;

  // staging addresses (inverse-swizzled global source, linear LDS dest)
  const int rA = tid >> 2;
  const int csrc = (tid & 3) ^ ((rA >> 1) & 3);
  const u16* pA = A  + (size_t)((size_t)mb * 256 + rA) * K + (size_t)ks0 * 32 + csrc * 8;
  const u16* pB = Bt + (size_t)((size_t)nb * 256 + rA) * K + (size_t)ks0 * 32 + csrc * 8;
  const size_t rowskip = (size_t)128 * K;
  u16* dA = lds + wid * 512;
  u16* dB = lds + 8192 + wid * 512;

  // swizzled read offsets (loop-invariant per lane)
  int offA[8], offB[4];
  #pragma unroll
  for (int m = 0; m < 8; ++m) {
    int r = wm * 128 + m * 16 + lrow;
    offA[m] = r * 32 + ((c0 ^ ((r >> 1) & 3)) << 3);
  }
  #pragma unroll
  for (int n = 0; n < 4; ++n) {
    int r = wn * 64 + n * 16 + lrow;
    offB[n] = 8192 + r * 32 + ((c0 ^ ((r >> 1) & 3)) << 3);
  }

  f32x4 acc[8][4];
  #pragma unroll
  for (int m = 0; m < 8; ++m)
    #pragma unroll
    for (int n = 0; n < 4; ++n) acc[m][n] = f32x4{0.f, 0.f, 0.f, 0.f};

  // prologue: stage units 0,1,2 into slots 0,1,2 (12 loads/thread in flight)
  #pragma unroll
  for (int u = 0; u < 3; ++u) {
    const u16* a = pA + u * 32;
    const u16* b = pB + u * 32;
    u16* da = dA + u * 16384;
    u16* db = dB + u * 16384;
    gload16(a, da);            gload16(a + rowskip, da + 4096);
    gload16(b, db);            gload16(b + rowskip, db + 4096);
  }

  for (int t = 0; t < kunits; ++t) {
    // in flight: units t,t+1,t+2 (12 loads) -> wait oldest 4 (unit t), keep 8
    asm volatile("s_waitcnt vmcnt(8)" ::: "memory");
    __builtin_amdgcn_s_barrier();
    __builtin_amdgcn_sched_barrier(0);

    // stage unit t+3 into slot (t+3)&3 == (t-1)&3 (read-complete by barrier)
    {
      int su = (t + 3 < kunits) ? (t + 3) : (kunits - 1);
      const u16* a = pA + (size_t)su * 32;
      const u16* b = pB + (size_t)su * 32;
      int so = ((t + 3) & 3) * 16384;
      u16* da = dA + so;
      u16* db = dB + so;
      gload16(a, da);          gload16(a + rowskip, da + 4096);
      gload16(b, db);          gload16(b + rowskip, db + 4096);
    }

    const u16* sl = lds + (t & 3) * 16384;
    bf16x8 af[8], bg[4];
    // lead-in: B fragments + first two A fragments
    bg[0] = *reinterpret_cast<const bf16x8*>(sl + offB[0]);
    bg[1] = *reinterpret_cast<const bf16x8*>(sl + offB[1]);
    bg[2] = *reinterpret_cast<const bf16x8*>(sl + offB[2]);
    bg[3] = *reinterpret_cast<const bf16x8*>(sl + offB[3]);
    af[0] = *reinterpret_cast<const bf16x8*>(sl + offA[0]);
    af[1] = *reinterpret_cast<const bf16x8*>(sl + offA[1]);
    __builtin_amdgcn_sched_barrier(0);

    // pipelined segments: read af[m+2] while MFMAing row m
    #pragma unroll
    for (int m = 0; m < 8; ++m) {
      if (m < 6)
        af[m + 2] = *reinterpret_cast<const bf16x8*>(sl + offA[m + 2]);
      __builtin_amdgcn_sched_barrier(0);
      __builtin_amdgcn_s_setprio(1);
      acc[m][0] = __builtin_amdgcn_mfma_f32_16x16x32_bf16(af[m], bg[0], acc[m][0], 0, 0, 0);
      acc[m][1] = __builtin_amdgcn_mfma_f32_16x16x32_bf16(af[m], bg[1], acc[m][1], 0, 0, 0);
      acc[m][2] = __builtin_amdgcn_mfma_f32_16x16x32_bf16(af[m], bg[2], acc[m][2], 0, 0, 0);
      acc[m][3] = __builtin_amdgcn_mfma_f32_16x16x32_bf16(af[m], bg[3], acc[m][3], 0, 0, 0);
      __builtin_amdgcn_s_setprio(0);
      __builtin_amdgcn_sched_barrier(0);
    }
    // no trailing barrier: next phase's barrier provides the cross-wave sync
  }

  // epilogue: write f32 partials (NT: keep the partial stream out of L2/L3)
  float* C = Cp + (size_t)sb * M * N;
  #pragma unroll
  for (int m = 0; m < 8; ++m) {
    const int rb = mb * 256 + wm * 128 + m * 16 + (lane >> 4) * 4;
    #pragma unroll
    for (int n = 0; n < 4; ++n) {
      const int col = nb * 256 + wn * 64 + n * 16 + (lane & 15);
      #pragma unroll
      for (int j2 = 0; j2 < 4; ++j2)
        __builtin_nontemporal_store(acc[m][n][j2], &C[(size_t)(rb + j2) * N + col]);
    }
  }
}

// ---------------------------------------------------------------------------
// 128x128 m97-structure GEMM for the small layers 2/3
// ---------------------------------------------------------------------------
__global__ __launch_bounds__(256) void gemm_bf16(
    const u16* __restrict__ A, const u16* __restrict__ Bt,
    float* __restrict__ Cp, int M, int N, int K, int kps)
{
  __shared__ __align__(16) u16 lA[128 * 32];
  __shared__ __align__(16) u16 lB[128 * 32];
  const int tid = threadIdx.x;
  const int mb = blockIdx.x, nb = blockIdx.y, sb = blockIdx.z;
  const int w = tid >> 6, lane = tid & 63;
  const int wr = (w >> 1) * 64, wc = (w & 1) * 64;
  const int lrow = lane & 15, lko = (lane >> 4) * 8;

  f32x4 acc[4][4];
  #pragma unroll
  for (int m = 0; m < 4; ++m)
    #pragma unroll
    for (int n = 0; n < 4; ++n) acc[m][n] = f32x4{0.f, 0.f, 0.f, 0.f};

  const u16* Ab = A + (size_t)mb * 128 * K;
  const u16* Bb = Bt + (size_t)nb * 128 * K;
  const int r0 = tid >> 2, inn = (tid & 3) * 8;
  const int l0 = (tid & ~63) * 8, l1 = ((256 + tid) & ~63) * 8;

  const int ks1 = (sb + 1) * kps;
  for (int ks = sb * kps; ks < ks1; ++ks) {
    const int k0 = ks * 32;
    __syncthreads();
    gload16(Ab + (size_t)r0 * K + k0 + inn,        lA + l0);
    gload16(Ab + (size_t)(r0 + 64) * K + k0 + inn, lA + l1);
    gload16(Bb + (size_t)r0 * K + k0 + inn,        lB + l0);
    gload16(Bb + (size_t)(r0 + 64) * K + k0 + inn, lB + l1);
    __syncthreads();
    bf16x8 af[4], bg[4];
    #pragma unroll
    for (int m = 0; m < 4; ++m)
      af[m] = *reinterpret_cast<const bf16x8*>(&lA[(wr + m * 16 + lrow) * 32 + lko]);
    #pragma unroll
    for (int n = 0; n < 4; ++n)
      bg[n] = *reinterpret_cast<const bf16x8*>(&lB[(wc + n * 16 + lrow) * 32 + lko]);
    #pragma unroll
    for (int m = 0; m < 4; ++m)
      #pragma unroll
      for (int n = 0; n < 4; ++n)
        acc[m][n] = __builtin_amdgcn_mfma_f32_16x16x32_bf16(af[m], bg[n], acc[m][n], 0, 0, 0);
  }

  float* C = Cp + (size_t)sb * M * N;
  #pragma unroll
  for (int m = 0; m < 4; ++m) {
    const int rb = mb * 128 + wr + m * 16 + (lane >> 4) * 4;
    #pragma unroll
    for (int n = 0; n < 4; ++n) {
      const int col = nb * 128 + wc + n * 16 + (lane & 15);
      #pragma unroll
      for (int j = 0; j < 4; ++j)
        __builtin_nontemporal_store(acc[m][n][j], &C[(size_t)(rb + j) * N + col]);
    }
  }
}

// ---------------------------------------------------------------------------
// Split-K reduce + bias + relu (+ cast); NT loads on the partial stream
// ---------------------------------------------------------------------------
__global__ __launch_bounds__(256) void reduce_bias_relu_bf16(
    const float* __restrict__ part, int S, size_t MN,
    const float* __restrict__ bias, int nmask, u16* __restrict__ out)
{
  for (size_t i = blockIdx.x * 256ull + threadIdx.x; i < MN; i += (size_t)gridDim.x * 256) {
    float s = 0.f;
    for (int k = 0; k < S; ++k) s += __builtin_nontemporal_load(&part[(size_t)k * MN + i]);
    s += bias[i & nmask];
    out[i] = f2bf(fmaxf(s, 0.f));
  }
}

__global__ __launch_bounds__(256) void reduce_bias_relu_f32(
    const float* __restrict__ part, int S, size_t MN,
    const float* __restrict__ bias, int nmask, float* __restrict__ out)
{
  for (size_t i = blockIdx.x * 256ull + threadIdx.x; i < MN; i += (size_t)gridDim.x * 256) {
    float s = 0.f;
    for (int k = 0; k < S; ++k) s += __builtin_nontemporal_load(&part[(size_t)k * MN + i]);
    s += bias[i & nmask];
    out[i] = fmaxf(s, 0.f);
  }
}

// ---------------------------------------------------------------------------
// Final: out[b] = h3[b,:] . W_out + b_out   (one wave per row)
// ---------------------------------------------------------------------------
__global__ __launch_bounds__(256) void final_dot(
    const float* __restrict__ h3, const float* __restrict__ Wout,
    const float* __restrict__ bout, float* __restrict__ out)
{
  const int row = blockIdx.x * 4 + (threadIdx.x >> 6);
  const int lane = threadIdx.x & 63;
  const float* hr = h3 + (size_t)row * HD3;
  float s = 0.f;
  #pragma unroll
  for (int i = 0; i < 4; ++i) s += hr[lane + i * 64] * Wout[lane + i * 64];
  #pragma unroll
  for (int off = 32; off; off >>= 1) s += __shfl_down(s, off, 64);
  if (lane == 0) out[row] = s + bout[0];
}

// ---------------------------------------------------------------------------
extern "C" void kernel_launch(void* const* d_in, const int* in_sizes, int n_in,
                              void* d_out, int out_size, void* d_ws, size_t ws_size,
                              hipStream_t stream)
{
  const int*   cat    = (const int*)  d_in[0];
  const float* num    = (const float*)d_in[1];
  const float* tables = (const float*)d_in[2];
  const float* nemb   = (const float*)d_in[3];
  const float* Wse1   = (const float*)d_in[4];
  const float* Wse2   = (const float*)d_in[5];
  const float* Wbil   = (const float*)d_in[6];
  const float* Wd1    = (const float*)d_in[7];
  const float* bd1    = (const float*)d_in[8];
  const float* Wd2    = (const float*)d_in[9];
  const float* bd2    = (const float*)d_in[10];
  const float* Wd3    = (const float*)d_in[11];
  const float* bd3    = (const float*)d_in[12];
  const float* Wout   = (const float*)d_in[13];
  const float* bout   = (const float*)d_in[14];

  char* ws = (char*)d_ws;
  // ws layout (total 311,230,464 B — round-3 proven footprint):
  u16*   hid  = (u16*)  (ws + 0ull);           // 194,248,704  bf16 [4096][23712]
  u16*   W1t  = (u16*)  (ws + 194248704ull);   //  48,562,176  bf16 [1024][23712]
  float* part = (float*)(ws + 242810880ull);   //  67,108,864  f32 splitK partials (S<=4)
  u16*   W2t  = (u16*)  (ws + 309919744ull);   //   1,048,576  bf16 [512][1024]
  u16*   W3t  = (u16*)  (ws + 310968320ull);   //     262,144  bf16 [256][512]
  // dead-hid region reuse (hid consumed by gemm1 before these are written):
  u16*   h1b  = (u16*)  (ws + 0ull);           //   8,388,608  bf16 [4096][1024]
  u16*   h2b  = (u16*)  (ws + 8388608ull);     //   4,194,304  bf16 [4096][512]
  float* h3f  = (float*)(ws + 12582912ull);    //   4,194,304  f32  [4096][256]

  transpose_cast<<<dim3(KHID / 32, HD1 / 32), 256, 0, stream>>>(Wd1, W1t, KHID, HD1);
  transpose_cast<<<dim3(HD1 / 32, HD2 / 32), 256, 0, stream>>>(Wd2, W2t, HD1, HD2);
  transpose_cast<<<dim3(HD2 / 32, HD3 / 32), 256, 0, stream>>>(Wd3, W3t, HD2, HD3);
  fuse_front<<<BATCH, 256, 0, stream>>>(cat, num, tables, nemb, Wse1, Wse2, Wbil, hid);

  // layer 1: [4096 x 23712] @ [23712 x 1024], 256^2 pipelined,
  // split-K=4 uneven (186/186/186/183 K-units), 1D grid 256 = exact CU fill
  gemm8_bf16<<<256, 512, 0, stream>>>(hid, W1t, part, BATCH, HD1, KHID, 741, 186);
  reduce_bias_relu_bf16<<<2048, 256, 0, stream>>>(part, 4, (size_t)BATCH * HD1, bd1, HD1 - 1, h1b);

  // layer 2: [4096 x 1024] @ [1024 x 512], split-K=2 (32 = 2*16)
  gemm_bf16<<<dim3(BATCH / 128, HD2 / 128, 2), 256, 0, stream>>>(h1b, W2t, part, BATCH, HD2, HD1, 16);
  reduce_bias_relu_bf16<<<2048, 256, 0, stream>>>(part, 2, (size_t)BATCH * HD2, bd2, HD2 - 1, h2b);

  // layer 3: [4096 x 512] @ [512 x 256], split-K=4 (16 = 4*4)
  gemm_bf16<<<dim3(BATCH / 128, HD3 / 128, 4), 256, 0, stream>>>(h2b, W3t, part, BATCH, HD3, HD2, 4);
  reduce_bias_relu_f32<<<2048, 256, 0, stream>>>(part, 4, (size_t)BATCH * HD3, bd3, HD3 - 1, h3f);

  final_dot<<<BATCH / 4, 256, 0, stream>>>(h3f, Wout, bout, (float*)d_out);
}

// Round 8
// 364.987 us; speedup vs baseline: 1.0522x; 1.0522x over previous
//
#include <hip/hip_runtime.h>

typedef unsigned short u16;
typedef __attribute__((ext_vector_type(8))) __bf16 bf16x8;
typedef __attribute__((ext_vector_type(4))) float f32x4;

#define NF    39
#define NNUM  13
#define NCAT  26
#define VOC   100000
#define NPAIR 741
#define KHID  23712   /* 2*741*16 */
#define BATCH 4096
#define HD1   1024
#define HD2   512
#define HD3   256

__device__ __forceinline__ u16 f2bf(float f) {
  unsigned u = __builtin_bit_cast(unsigned, f);
  return (u16)((u + 0x7fffu + ((u >> 16) & 1u)) >> 16);   // RNE
}

__device__ __forceinline__ void gload16(const void* g, void* l) {
  __builtin_amdgcn_global_load_lds((const __attribute__((address_space(1))) void*)g,
                                   (__attribute__((address_space(3))) void*)l, 16, 0, 0);
}

// ---------------------------------------------------------------------------
// Front end: gather + SE + bilinear proj + pairwise products -> hid bf16 [B][23712]
// ---------------------------------------------------------------------------
__global__ __launch_bounds__(256) void fuse_front(
    const int* __restrict__ cat, const float* __restrict__ num,
    const float* __restrict__ tables, const float* __restrict__ nemb,
    const float* __restrict__ Wse1, const float* __restrict__ Wse2,
    const float* __restrict__ Wbil, u16* __restrict__ hid)
{
  __shared__ float xs[NF][16];
  __shared__ float wb[NF][16][16];   // [f][e][d]
  __shared__ float pr[NF][16];       // proj
  __shared__ float Zs[NF], Ts[NNUM], As[NF];
  __shared__ unsigned char pis[NPAIR], pjs[NPAIR];

  const int b = blockIdx.x;
  const int tid = threadIdx.x;

  for (int i = tid; i < NF * 256; i += 256) ((float*)wb)[i] = Wbil[i];

  for (int t = tid; t < NNUM * 16; t += 256) {
    int f = t >> 4, e = t & 15;
    xs[f][e] = num[b * NNUM + f] * nemb[t];
  }
  for (int t = tid; t < NCAT * 16; t += 256) {
    int c = t >> 4, e = t & 15;
    int cv = cat[b * NCAT + c];
    xs[NNUM + c][e] = tables[((size_t)c * VOC + cv) * 16 + e];
  }
  for (int p = tid; p < NPAIR; p += 256) {
    int i = 0, rs = 0;
    while (p >= rs + (NF - 1 - i)) { rs += NF - 1 - i; ++i; }
    pis[p] = (unsigned char)i;
    pjs[p] = (unsigned char)(i + 1 + (p - rs));
  }
  __syncthreads();

  if (tid < NF) {
    float s = 0.f;
    #pragma unroll
    for (int e = 0; e < 16; ++e) s += xs[tid][e];
    Zs[tid] = s * (1.f / 16.f);
  }
  __syncthreads();
  if (tid < NNUM) {
    float s = 0.f;
    for (int f = 0; f < NF; ++f) s += Zs[f] * Wse1[f * NNUM + tid];
    Ts[tid] = fmaxf(s, 0.f);
  }
  __syncthreads();
  if (tid < NF) {
    float s = 0.f;
    for (int r = 0; r < NNUM; ++r) s += Ts[r] * Wse2[r * NF + tid];
    As[tid] = fmaxf(s, 0.f);
  }
  for (int t = tid; t < NF * 16; t += 256) {
    int f = t >> 4, d = t & 15;
    float s = 0.f;
    #pragma unroll
    for (int e = 0; e < 16; ++e) s += xs[f][e] * wb[f][e][d];
    pr[f][d] = s;
  }
  __syncthreads();

  u16* hr = hid + (size_t)b * KHID;
  for (int idx = tid; idx < NPAIR * 16; idx += 256) {
    int p = idx >> 4, e = idx & 15;
    int i = pis[p], j = pjs[p];
    float bv = pr[i][e] * xs[j][e];
    hr[NPAIR * 16 + idx] = f2bf(bv);
    hr[idx] = f2bf(As[i] * As[j] * bv);
  }
}

// ---------------------------------------------------------------------------
// Transpose + cast: in f32 [K][N] -> out bf16 [N][K]
// ---------------------------------------------------------------------------
__global__ __launch_bounds__(256) void transpose_cast(
    const float* __restrict__ in, u16* __restrict__ out, int K, int N)
{
  __shared__ float t[32][33];
  const int k0 = blockIdx.x * 32, n0 = blockIdx.y * 32;
  const int c = threadIdx.x & 31, r = threadIdx.x >> 5;
  #pragma unroll
  for (int it = 0; it < 4; ++it)
    t[r + it * 8][c] = in[(size_t)(k0 + r + it * 8) * N + n0 + c];
  __syncthreads();
  #pragma unroll
  for (int it = 0; it < 4; ++it)
    out[(size_t)(n0 + r + it * 8) * K + k0 + c] = f2bf(t[c][r + it * 8]);
}

// ---------------------------------------------------------------------------
// 256x256 8-wave m201-style fine-phase GEMM. BK=64, per-K-tile 4 phases of
// 16 MFMA; LDS = A-ring 4x16KB + B-ring 4x16KB (granule = 256x32 kk-half).
// Staging partition per tile tau: P0->A(tau+1,kk1), P1->B(tau+2,kk0),
// P2->A(tau+2,kk0), P3->B(tau+2,kk1); each target slot freed >=1 phase prior.
// Counted waits only: vmcnt(10) prologue, vmcnt(8) at P1/P3 ends (forces the
// two granules read 2 phases later; 4 granules stay in flight).
// ---------------------------------------------------------------------------
__global__ __launch_bounds__(512, 2) void gemm8p_bf16(
    const u16* __restrict__ A, const u16* __restrict__ Bt,
    float* __restrict__ Cp, int M, int N, int K, int totku, int kpb)
{
  __shared__ __align__(16) u16 lds[65536];   // 128 KiB: A slots @0, B slots @32768

  const int tid = threadIdx.x;
  const int wid = tid >> 6, lane = tid & 63;

  // 2D-grouped bijective XCD swizzle (round-6 proven)
  const int d = blockIdx.x;
  const int x = d & 7, jj = d >> 3;
  const int mb = ((x & 3) << 2) | (jj & 3);
  const int nb = (jj >> 2) & 3;
  const int sb = ((x >> 2) << 1) | (jj >> 4);

  const int ks0 = sb * kpb;
  const int kunits = (totku - ks0 < kpb) ? (totku - ks0) : kpb;   // 32-col units
  const int ftiles = kunits >> 1;                                  // 64-col tiles

  const int wm = wid >> 2, wn = wid & 3;        // 2M x 4N waves
  const int lrow = lane & 15, c0 = lane >> 4;

  // staging source (inverse-swizzled global, linear LDS dest)
  const int rr = tid >> 2, cc = tid & 3, csrc = cc ^ ((rr >> 1) & 3);
  const u16* pAg = A  + (size_t)((size_t)mb * 256 + rr) * K + (size_t)ks0 * 32 + csrc * 8;
  const u16* pBg = Bt + (size_t)((size_t)nb * 256 + rr) * K + (size_t)ks0 * 32 + csrc * 8;
  const size_t rsk = (size_t)128 * K;
  const int dstoff = tid * 8;   // u16 units

  // swizzled granule-relative read offsets
  int offA[8], offB[4];
  #pragma unroll
  for (int m = 0; m < 8; ++m) {
    int r = wm * 128 + m * 16 + lrow;
    offA[m] = r * 32 + ((c0 ^ ((r >> 1) & 3)) << 3);
  }
  #pragma unroll
  for (int n = 0; n < 4; ++n) {
    int r = wn * 64 + n * 16 + lrow;
    offB[n] = r * 32 + ((c0 ^ ((r >> 1) & 3)) << 3);
  }

#define STAGE_A(g) { int sg = ((g) < kunits) ? (g) : (kunits - 1);          \
    const u16* s_ = pAg + (size_t)sg * 32;                                   \
    u16* dp_ = lds + (((g) & 3) * 8192) + dstoff;                            \
    gload16(s_, dp_); gload16(s_ + rsk, dp_ + 4096); }
#define STAGE_B(g) { int sg = ((g) < kunits) ? (g) : (kunits - 1);          \
    const u16* s_ = pBg + (size_t)sg * 32;                                   \
    u16* dp_ = lds + 32768 + (((g) & 3) * 8192) + dstoff;                    \
    gload16(s_, dp_); gload16(s_ + rsk, dp_ + 4096); }

  f32x4 acc[8][4];
  #pragma unroll
  for (int m = 0; m < 8; ++m)
    #pragma unroll
    for (int n = 0; n < 4; ++n) acc[m][n] = f32x4{0.f, 0.f, 0.f, 0.f};

  // prologue: A0,B0,A1,B1,A2,B2,B3 (oldest-first; loop stages A3/B4/... next)
  STAGE_A(0); STAGE_B(0); STAGE_A(1); STAGE_B(1); STAGE_A(2); STAGE_B(2); STAGE_B(3);
  asm volatile("s_waitcnt vmcnt(10)" ::: "memory");   // forces A0,B0
  __builtin_amdgcn_s_barrier();

  bf16x8 a0, a1, a2, a3, bg0, bg1, bg2, bg3;

  for (int tt = 0; tt < ftiles; ++tt) {
    const int g0 = tt << 1;
    const u16* As0 = lds + ((g0 & 3) * 8192);
    const u16* As1 = lds + (((g0 + 1) & 3) * 8192);
    const u16* Bs0 = lds + 32768 + ((g0 & 3) * 8192);
    const u16* Bs1 = lds + 32768 + (((g0 + 1) & 3) * 8192);

    // ---- P0: af(m0-3,kk0) + bg(kk0); stage A(g0+3)
    a0 = *reinterpret_cast<const bf16x8*>(As0 + offA[0]);
    a1 = *reinterpret_cast<const bf16x8*>(As0 + offA[1]);
    a2 = *reinterpret_cast<const bf16x8*>(As0 + offA[2]);
    a3 = *reinterpret_cast<const bf16x8*>(As0 + offA[3]);
    bg0 = *reinterpret_cast<const bf16x8*>(Bs0 + offB[0]);
    bg1 = *reinterpret_cast<const bf16x8*>(Bs0 + offB[1]);
    bg2 = *reinterpret_cast<const bf16x8*>(Bs0 + offB[2]);
    bg3 = *reinterpret_cast<const bf16x8*>(Bs0 + offB[3]);
    STAGE_A(g0 + 3);
    __builtin_amdgcn_sched_barrier(0);
    __builtin_amdgcn_s_barrier();
    asm volatile("s_waitcnt lgkmcnt(0)" ::: "memory");
    __builtin_amdgcn_sched_barrier(0);
    __builtin_amdgcn_s_setprio(1);
    acc[0][0] = __builtin_amdgcn_mfma_f32_16x16x32_bf16(a0, bg0, acc[0][0], 0, 0, 0);
    acc[0][1] = __builtin_amdgcn_mfma_f32_16x16x32_bf16(a0, bg1, acc[0][1], 0, 0, 0);
    acc[0][2] = __builtin_amdgcn_mfma_f32_16x16x32_bf16(a0, bg2, acc[0][2], 0, 0, 0);
    acc[0][3] = __builtin_amdgcn_mfma_f32_16x16x32_bf16(a0, bg3, acc[0][3], 0, 0, 0);
    acc[1][0] = __builtin_amdgcn_mfma_f32_16x16x32_bf16(a1, bg0, acc[1][0], 0, 0, 0);
    acc[1][1] = __builtin_amdgcn_mfma_f32_16x16x32_bf16(a1, bg1, acc[1][1], 0, 0, 0);
    acc[1][2] = __builtin_amdgcn_mfma_f32_16x16x32_bf16(a1, bg2, acc[1][2], 0, 0, 0);
    acc[1][3] = __builtin_amdgcn_mfma_f32_16x16x32_bf16(a1, bg3, acc[1][3], 0, 0, 0);
    acc[2][0] = __builtin_amdgcn_mfma_f32_16x16x32_bf16(a2, bg0, acc[2][0], 0, 0, 0);
    acc[2][1] = __builtin_amdgcn_mfma_f32_16x16x32_bf16(a2, bg1, acc[2][1], 0, 0, 0);
    acc[2][2] = __builtin_amdgcn_mfma_f32_16x16x32_bf16(a2, bg2, acc[2][2], 0, 0, 0);
    acc[2][3] = __builtin_amdgcn_mfma_f32_16x16x32_bf16(a2, bg3, acc[2][3], 0, 0, 0);
    acc[3][0] = __builtin_amdgcn_mfma_f32_16x16x32_bf16(a3, bg0, acc[3][0], 0, 0, 0);
    acc[3][1] = __builtin_amdgcn_mfma_f32_16x16x32_bf16(a3, bg1, acc[3][1], 0, 0, 0);
    acc[3][2] = __builtin_amdgcn_mfma_f32_16x16x32_bf16(a3, bg2, acc[3][2], 0, 0, 0);
    acc[3][3] = __builtin_amdgcn_mfma_f32_16x16x32_bf16(a3, bg3, acc[3][3], 0, 0, 0);
    __builtin_amdgcn_s_setprio(0);
    __builtin_amdgcn_sched_barrier(0);
    __builtin_amdgcn_s_barrier();

    // ---- P1: af(m4-7,kk0), bg reused; stage B(g0+4); vmcnt(8) at end
    a0 = *reinterpret_cast<const bf16x8*>(As0 + offA[4]);
    a1 = *reinterpret_cast<const bf16x8*>(As0 + offA[5]);
    a2 = *reinterpret_cast<const bf16x8*>(As0 + offA[6]);
    a3 = *reinterpret_cast<const bf16x8*>(As0 + offA[7]);
    STAGE_B(g0 + 4);
    __builtin_amdgcn_sched_barrier(0);
    __builtin_amdgcn_s_barrier();
    asm volatile("s_waitcnt lgkmcnt(0)" ::: "memory");
    __builtin_amdgcn_sched_barrier(0);
    __builtin_amdgcn_s_setprio(1);
    acc[4][0] = __builtin_amdgcn_mfma_f32_16x16x32_bf16(a0, bg0, acc[4][0], 0, 0, 0);
    acc[4][1] = __builtin_amdgcn_mfma_f32_16x16x32_bf16(a0, bg1, acc[4][1], 0, 0, 0);
    acc[4][2] = __builtin_amdgcn_mfma_f32_16x16x32_bf16(a0, bg2, acc[4][2], 0, 0, 0);
    acc[4][3] = __builtin_amdgcn_mfma_f32_16x16x32_bf16(a0, bg3, acc[4][3], 0, 0, 0);
    acc[5][0] = __builtin_amdgcn_mfma_f32_16x16x32_bf16(a1, bg0, acc[5][0], 0, 0, 0);
    acc[5][1] = __builtin_amdgcn_mfma_f32_16x16x32_bf16(a1, bg1, acc[5][1], 0, 0, 0);
    acc[5][2] = __builtin_amdgcn_mfma_f32_16x16x32_bf16(a1, bg2, acc[5][2], 0, 0, 0);
    acc[5][3] = __builtin_amdgcn_mfma_f32_16x16x32_bf16(a1, bg3, acc[5][3], 0, 0, 0);
    acc[6][0] = __builtin_amdgcn_mfma_f32_16x16x32_bf16(a2, bg0, acc[6][0], 0, 0, 0);
    acc[6][1] = __builtin_amdgcn_mfma_f32_16x16x32_bf16(a2, bg1, acc[6][1], 0, 0, 0);
    acc[6][2] = __builtin_amdgcn_mfma_f32_16x16x32_bf16(a2, bg2, acc[6][2], 0, 0, 0);
    acc[6][3] = __builtin_amdgcn_mfma_f32_16x16x32_bf16(a2, bg3, acc[6][3], 0, 0, 0);
    acc[7][0] = __builtin_amdgcn_mfma_f32_16x16x32_bf16(a3, bg0, acc[7][0], 0, 0, 0);
    acc[7][1] = __builtin_amdgcn_mfma_f32_16x16x32_bf16(a3, bg1, acc[7][1], 0, 0, 0);
    acc[7][2] = __builtin_amdgcn_mfma_f32_16x16x32_bf16(a3, bg2, acc[7][2], 0, 0, 0);
    acc[7][3] = __builtin_amdgcn_mfma_f32_16x16x32_bf16(a3, bg3, acc[7][3], 0, 0, 0);
    __builtin_amdgcn_s_setprio(0);
    __builtin_amdgcn_sched_barrier(0);
    asm volatile("s_waitcnt vmcnt(8)" ::: "memory");
    __builtin_amdgcn_s_barrier();

    // ---- P2: af(m0-3,kk1) + bg(kk1); stage A(g0+4)
    a0 = *reinterpret_cast<const bf16x8*>(As1 + offA[0]);
    a1 = *reinterpret_cast<const bf16x8*>(As1 + offA[1]);
    a2 = *reinterpret_cast<const bf16x8*>(As1 + offA[2]);
    a3 = *reinterpret_cast<const bf16x8*>(As1 + offA[3]);
    bg0 = *reinterpret_cast<const bf16x8*>(Bs1 + offB[0]);
    bg1 = *reinterpret_cast<const bf16x8*>(Bs1 + offB[1]);
    bg2 = *reinterpret_cast<const bf16x8*>(Bs1 + offB[2]);
    bg3 = *reinterpret_cast<const bf16x8*>(Bs1 + offB[3]);
    STAGE_A(g0 + 4);
    __builtin_amdgcn_sched_barrier(0);
    __builtin_amdgcn_s_barrier();
    asm volatile("s_waitcnt lgkmcnt(0)" ::: "memory");
    __builtin_amdgcn_sched_barrier(0);
    __builtin_amdgcn_s_setprio(1);
    acc[0][0] = __builtin_amdgcn_mfma_f32_16x16x32_bf16(a0, bg0, acc[0][0], 0, 0, 0);
    acc[0][1] = __builtin_amdgcn_mfma_f32_16x16x32_bf16(a0, bg1, acc[0][1], 0, 0, 0);
    acc[0][2] = __builtin_amdgcn_mfma_f32_16x16x32_bf16(a0, bg2, acc[0][2], 0, 0, 0);
    acc[0][3] = __builtin_amdgcn_mfma_f32_16x16x32_bf16(a0, bg3, acc[0][3], 0, 0, 0);
    acc[1][0] = __builtin_amdgcn_mfma_f32_16x16x32_bf16(a1, bg0, acc[1][0], 0, 0, 0);
    acc[1][1] = __builtin_amdgcn_mfma_f32_16x16x32_bf16(a1, bg1, acc[1][1], 0, 0, 0);
    acc[1][2] = __builtin_amdgcn_mfma_f32_16x16x32_bf16(a1, bg2, acc[1][2], 0, 0, 0);
    acc[1][3] = __builtin_amdgcn_mfma_f32_16x16x32_bf16(a1, bg3, acc[1][3], 0, 0, 0);
    acc[2][0] = __builtin_amdgcn_mfma_f32_16x16x32_bf16(a2, bg0, acc[2][0], 0, 0, 0);
    acc[2][1] = __builtin_amdgcn_mfma_f32_16x16x32_bf16(a2, bg1, acc[2][1], 0, 0, 0);
    acc[2][2] = __builtin_amdgcn_mfma_f32_16x16x32_bf16(a2, bg2, acc[2][2], 0, 0, 0);
    acc[2][3] = __builtin_amdgcn_mfma_f32_16x16x32_bf16(a2, bg3, acc[2][3], 0, 0, 0);
    acc[3][0] = __builtin_amdgcn_mfma_f32_16x16x32_bf16(a3, bg0, acc[3][0], 0, 0, 0);
    acc[3][1] = __builtin_amdgcn_mfma_f32_16x16x32_bf16(a3, bg1, acc[3][1], 0, 0, 0);
    acc[3][2] = __builtin_amdgcn_mfma_f32_16x16x32_bf16(a3, bg2, acc[3][2], 0, 0, 0);
    acc[3][3] = __builtin_amdgcn_mfma_f32_16x16x32_bf16(a3, bg3, acc[3][3], 0, 0, 0);
    __builtin_amdgcn_s_setprio(0);
    __builtin_amdgcn_sched_barrier(0);
    __builtin_amdgcn_s_barrier();

    // ---- P3: af(m4-7,kk1); stage B(g0+5); vmcnt(8) at end
    a0 = *reinterpret_cast<const bf16x8*>(As1 + offA[4]);
    a1 = *reinterpret_cast<const bf16x8*>(As1 + offA[5]);
    a2 = *reinterpret_cast<const bf16x8*>(As1 + offA[6]);
    a3 = *reinterpret_cast<const bf16x8*>(As1 + offA[7]);
    STAGE_B(g0 + 5);
    __builtin_amdgcn_sched_barrier(0);
    __builtin_amdgcn_s_barrier();
    asm volatile("s_waitcnt lgkmcnt(0)" ::: "memory");
    __builtin_amdgcn_sched_barrier(0);
    __builtin_amdgcn_s_setprio(1);
    acc[4][0] = __builtin_amdgcn_mfma_f32_16x16x32_bf16(a0, bg0, acc[4][0], 0, 0, 0);
    acc[4][1] = __builtin_amdgcn_mfma_f32_16x16x32_bf16(a0, bg1, acc[4][1], 0, 0, 0);
    acc[4][2] = __builtin_amdgcn_mfma_f32_16x16x32_bf16(a0, bg2, acc[4][2], 0, 0, 0);
    acc[4][3] = __builtin_amdgcn_mfma_f32_16x16x32_bf16(a0, bg3, acc[4][3], 0, 0, 0);
    acc[5][0] = __builtin_amdgcn_mfma_f32_16x16x32_bf16(a1, bg0, acc[5][0], 0, 0, 0);
    acc[5][1] = __builtin_amdgcn_mfma_f32_16x16x32_bf16(a1, bg1, acc[5][1], 0, 0, 0);
    acc[5][2] = __builtin_amdgcn_mfma_f32_16x16x32_bf16(a1, bg2, acc[5][2], 0, 0, 0);
    acc[5][3] = __builtin_amdgcn_mfma_f32_16x16x32_bf16(a1, bg3, acc[5][3], 0, 0, 0);
    acc[6][0] = __builtin_amdgcn_mfma_f32_16x16x32_bf16(a2, bg0, acc[6][0], 0, 0, 0);
    acc[6][1] = __builtin_amdgcn_mfma_f32_16x16x32_bf16(a2, bg1, acc[6][1], 0, 0, 0);
    acc[6][2] = __builtin_amdgcn_mfma_f32_16x16x32_bf16(a2, bg2, acc[6][2], 0, 0, 0);
    acc[6][3] = __builtin_amdgcn_mfma_f32_16x16x32_bf16(a2, bg3, acc[6][3], 0, 0, 0);
    acc[7][0] = __builtin_amdgcn_mfma_f32_16x16x32_bf16(a3, bg0, acc[7][0], 0, 0, 0);
    acc[7][1] = __builtin_amdgcn_mfma_f32_16x16x32_bf16(a3, bg1, acc[7][1], 0, 0, 0);
    acc[7][2] = __builtin_amdgcn_mfma_f32_16x16x32_bf16(a3, bg2, acc[7][2], 0, 0, 0);
    acc[7][3] = __builtin_amdgcn_mfma_f32_16x16x32_bf16(a3, bg3, acc[7][3], 0, 0, 0);
    __builtin_amdgcn_s_setprio(0);
    __builtin_amdgcn_sched_barrier(0);
    asm volatile("s_waitcnt vmcnt(8)" ::: "memory");
    __builtin_amdgcn_s_barrier();
  }

  // ---- tail: odd trailing 32-col unit (strip 3 only)
  if (kunits & 1) {
    asm volatile("s_waitcnt vmcnt(0)" ::: "memory");
    __builtin_amdgcn_s_barrier();
    const int g = kunits - 1;
    const u16* As = lds + ((g & 3) * 8192);
    const u16* Bs = lds + 32768 + ((g & 3) * 8192);
    bg0 = *reinterpret_cast<const bf16x8*>(Bs + offB[0]);
    bg1 = *reinterpret_cast<const bf16x8*>(Bs + offB[1]);
    bg2 = *reinterpret_cast<const bf16x8*>(Bs + offB[2]);
    bg3 = *reinterpret_cast<const bf16x8*>(Bs + offB[3]);
    #pragma unroll
    for (int m = 0; m < 8; ++m) {
      bf16x8 am = *reinterpret_cast<const bf16x8*>(As + offA[m]);
      acc[m][0] = __builtin_amdgcn_mfma_f32_16x16x32_bf16(am, bg0, acc[m][0], 0, 0, 0);
      acc[m][1] = __builtin_amdgcn_mfma_f32_16x16x32_bf16(am, bg1, acc[m][1], 0, 0, 0);
      acc[m][2] = __builtin_amdgcn_mfma_f32_16x16x32_bf16(am, bg2, acc[m][2], 0, 0, 0);
      acc[m][3] = __builtin_amdgcn_mfma_f32_16x16x32_bf16(am, bg3, acc[m][3], 0, 0, 0);
    }
  }
#undef STAGE_A
#undef STAGE_B

  // ---- epilogue: write f32 partials (NT)
  float* C = Cp + (size_t)sb * M * N;
  #pragma unroll
  for (int m = 0; m < 8; ++m) {
    const int rb = mb * 256 + wm * 128 + m * 16 + (lane >> 4) * 4;
    #pragma unroll
    for (int n = 0; n < 4; ++n) {
      const int col = nb * 256 + wn * 64 + n * 16 + (lane & 15);
      #pragma unroll
      for (int j2 = 0; j2 < 4; ++j2)
        __builtin_nontemporal_store(acc[m][n][j2], &C[(size_t)(rb + j2) * N + col]);
    }
  }
}

// ---------------------------------------------------------------------------
// 128x128 m97-structure GEMM for the small layers 2/3
// ---------------------------------------------------------------------------
__global__ __launch_bounds__(256) void gemm_bf16(
    const u16* __restrict__ A, const u16* __restrict__ Bt,
    float* __restrict__ Cp, int M, int N, int K, int kps)
{
  __shared__ __align__(16) u16 lA[128 * 32];
  __shared__ __align__(16) u16 lB[128 * 32];
  const int tid = threadIdx.x;
  const int mb = blockIdx.x, nb = blockIdx.y, sb = blockIdx.z;
  const int w = tid >> 6, lane = tid & 63;
  const int wr = (w >> 1) * 64, wc = (w & 1) * 64;
  const int lrow = lane & 15, lko = (lane >> 4) * 8;

  f32x4 acc[4][4];
  #pragma unroll
  for (int m = 0; m < 4; ++m)
    #pragma unroll
    for (int n = 0; n < 4; ++n) acc[m][n] = f32x4{0.f, 0.f, 0.f, 0.f};

  const u16* Ab = A + (size_t)mb * 128 * K;
  const u16* Bb = Bt + (size_t)nb * 128 * K;
  const int r0 = tid >> 2, inn = (tid & 3) * 8;
  const int l0 = (tid & ~63) * 8, l1 = ((256 + tid) & ~63) * 8;

  const int ks1 = (sb + 1) * kps;
  for (int ks = sb * kps; ks < ks1; ++ks) {
    const int k0 = ks * 32;
    __syncthreads();
    gload16(Ab + (size_t)r0 * K + k0 + inn,        lA + l0);
    gload16(Ab + (size_t)(r0 + 64) * K + k0 + inn, lA + l1);
    gload16(Bb + (size_t)r0 * K + k0 + inn,        lB + l0);
    gload16(Bb + (size_t)(r0 + 64) * K + k0 + inn, lB + l1);
    __syncthreads();
    bf16x8 af[4], bg[4];
    #pragma unroll
    for (int m = 0; m < 4; ++m)
      af[m] = *reinterpret_cast<const bf16x8*>(&lA[(wr + m * 16 + lrow) * 32 + lko]);
    #pragma unroll
    for (int n = 0; n < 4; ++n)
      bg[n] = *reinterpret_cast<const bf16x8*>(&lB[(wc + n * 16 + lrow) * 32 + lko]);
    #pragma unroll
    for (int m = 0; m < 4; ++m)
      #pragma unroll
      for (int n = 0; n < 4; ++n)
        acc[m][n] = __builtin_amdgcn_mfma_f32_16x16x32_bf16(af[m], bg[n], acc[m][n], 0, 0, 0);
  }

  float* C = Cp + (size_t)sb * M * N;
  #pragma unroll
  for (int m = 0; m < 4; ++m) {
    const int rb = mb * 128 + wr + m * 16 + (lane >> 4) * 4;
    #pragma unroll
    for (int n = 0; n < 4; ++n) {
      const int col = nb * 128 + wc + n * 16 + (lane & 15);
      #pragma unroll
      for (int j = 0; j < 4; ++j)
        __builtin_nontemporal_store(acc[m][n][j], &C[(size_t)(rb + j) * N + col]);
    }
  }
}

// ---------------------------------------------------------------------------
// Split-K reduce + bias + relu (+ cast); NT loads on the partial stream
// ---------------------------------------------------------------------------
__global__ __launch_bounds__(256) void reduce_bias_relu_bf16(
    const float* __restrict__ part, int S, size_t MN,
    const float* __restrict__ bias, int nmask, u16* __restrict__ out)
{
  for (size_t i = blockIdx.x * 256ull + threadIdx.x; i < MN; i += (size_t)gridDim.x * 256) {
    float s = 0.f;
    for (int k = 0; k < S; ++k) s += __builtin_nontemporal_load(&part[(size_t)k * MN + i]);
    s += bias[i & nmask];
    out[i] = f2bf(fmaxf(s, 0.f));
  }
}

__global__ __launch_bounds__(256) void reduce_bias_relu_f32(
    const float* __restrict__ part, int S, size_t MN,
    const float* __restrict__ bias, int nmask, float* __restrict__ out)
{
  for (size_t i = blockIdx.x * 256ull + threadIdx.x; i < MN; i += (size_t)gridDim.x * 256) {
    float s = 0.f;
    for (int k = 0; k < S; ++k) s += __builtin_nontemporal_load(&part[(size_t)k * MN + i]);
    s += bias[i & nmask];
    out[i] = fmaxf(s, 0.f);
  }
}

// ---------------------------------------------------------------------------
// Final: out[b] = h3[b,:] . W_out + b_out   (one wave per row)
// ---------------------------------------------------------------------------
__global__ __launch_bounds__(256) void final_dot(
    const float* __restrict__ h3, const float* __restrict__ Wout,
    const float* __restrict__ bout, float* __restrict__ out)
{
  const int row = blockIdx.x * 4 + (threadIdx.x >> 6);
  const int lane = threadIdx.x & 63;
  const float* hr = h3 + (size_t)row * HD3;
  float s = 0.f;
  #pragma unroll
  for (int i = 0; i < 4; ++i) s += hr[lane + i * 64] * Wout[lane + i * 64];
  #pragma unroll
  for (int off = 32; off; off >>= 1) s += __shfl_down(s, off, 64);
  if (lane == 0) out[row] = s + bout[0];
}

// ---------------------------------------------------------------------------
extern "C" void kernel_launch(void* const* d_in, const int* in_sizes, int n_in,
                              void* d_out, int out_size, void* d_ws, size_t ws_size,
                              hipStream_t stream)
{
  const int*   cat    = (const int*)  d_in[0];
  const float* num    = (const float*)d_in[1];
  const float* tables = (const float*)d_in[2];
  const float* nemb   = (const float*)d_in[3];
  const float* Wse1   = (const float*)d_in[4];
  const float* Wse2   = (const float*)d_in[5];
  const float* Wbil   = (const float*)d_in[6];
  const float* Wd1    = (const float*)d_in[7];
  const float* bd1    = (const float*)d_in[8];
  const float* Wd2    = (const float*)d_in[9];
  const float* bd2    = (const float*)d_in[10];
  const float* Wd3    = (const float*)d_in[11];
  const float* bd3    = (const float*)d_in[12];
  const float* Wout   = (const float*)d_in[13];
  const float* bout   = (const float*)d_in[14];

  char* ws = (char*)d_ws;
  // ws layout (total 311,230,464 B — round-3 proven footprint):
  u16*   hid  = (u16*)  (ws + 0ull);           // 194,248,704  bf16 [4096][23712]
  u16*   W1t  = (u16*)  (ws + 194248704ull);   //  48,562,176  bf16 [1024][23712]
  float* part = (float*)(ws + 242810880ull);   //  67,108,864  f32 splitK partials (S<=4)
  u16*   W2t  = (u16*)  (ws + 309919744ull);   //   1,048,576  bf16 [512][1024]
  u16*   W3t  = (u16*)  (ws + 310968320ull);   //     262,144  bf16 [256][512]
  // dead-hid region reuse (hid consumed by gemm1 before these are written):
  u16*   h1b  = (u16*)  (ws + 0ull);           //   8,388,608  bf16 [4096][1024]
  u16*   h2b  = (u16*)  (ws + 8388608ull);     //   4,194,304  bf16 [4096][512]
  float* h3f  = (float*)(ws + 12582912ull);    //   4,194,304  f32  [4096][256]

  transpose_cast<<<dim3(KHID / 32, HD1 / 32), 256, 0, stream>>>(Wd1, W1t, KHID, HD1);
  transpose_cast<<<dim3(HD1 / 32, HD2 / 32), 256, 0, stream>>>(Wd2, W2t, HD1, HD2);
  transpose_cast<<<dim3(HD2 / 32, HD3 / 32), 256, 0, stream>>>(Wd3, W3t, HD2, HD3);
  fuse_front<<<BATCH, 256, 0, stream>>>(cat, num, tables, nemb, Wse1, Wse2, Wbil, hid);

  // layer 1: [4096 x 23712] @ [23712 x 1024], 256^2 fine-phase pipelined,
  // split-K=4 uneven (186/186/186/183 units of 32), 1D grid 256 = exact CU fill
  gemm8p_bf16<<<256, 512, 0, stream>>>(hid, W1t, part, BATCH, HD1, KHID, 741, 186);
  reduce_bias_relu_bf16<<<2048, 256, 0, stream>>>(part, 4, (size_t)BATCH * HD1, bd1, HD1 - 1, h1b);

  // layer 2: [4096 x 1024] @ [1024 x 512], split-K=2 (32 = 2*16)
  gemm_bf16<<<dim3(BATCH / 128, HD2 / 128, 2), 256, 0, stream>>>(h1b, W2t, part, BATCH, HD2, HD1, 16);
  reduce_bias_relu_bf16<<<2048, 256, 0, stream>>>(part, 2, (size_t)BATCH * HD2, bd2, HD2 - 1, h2b);

  // layer 3: [4096 x 512] @ [512 x 256], split-K=4 (16 = 4*4)
  gemm_bf16<<<dim3(BATCH / 128, HD3 / 128, 4), 256, 0, stream>>>(h2b, W3t, part, BATCH, HD3, HD2, 4);
  reduce_bias_relu_f32<<<2048, 256, 0, stream>>>(part, 4, (size_t)BATCH * HD3, bd3, HD3 - 1, h3f);

  final_dot<<<BATCH / 4, 256, 0, stream>>>(h3f, Wout, bout, (float*)d_out);
}

// Round 9
// 343.187 us; speedup vs baseline: 1.1190x; 1.0635x over previous
//
#include <hip/hip_runtime.h>

typedef unsigned short u16;
typedef __attribute__((ext_vector_type(8))) __bf16 bf16x8;
typedef __attribute__((ext_vector_type(4))) float f32x4;
typedef __attribute__((ext_vector_type(4))) unsigned short u16x4;
typedef __attribute__((ext_vector_type(8))) unsigned short u16x8;

#define NF    39
#define NNUM  13
#define NCAT  26
#define VOC   100000
#define NPAIR 741
#define KHID  23712   /* 2*741*16 */
#define BATCH 4096
#define HD1   1024
#define HD2   512
#define HD3   256

__device__ __forceinline__ u16 f2bf(float f) {
  unsigned u = __builtin_bit_cast(unsigned, f);
  return (u16)((u + 0x7fffu + ((u >> 16) & 1u)) >> 16);   // RNE
}

__device__ __forceinline__ void gload16(const void* g, void* l) {
  __builtin_amdgcn_global_load_lds((const __attribute__((address_space(1))) void*)g,
                                   (__attribute__((address_space(3))) void*)l, 16, 0, 0);
}

// ---------------------------------------------------------------------------
// Front end: gather + SE + bilinear proj + pairwise products -> hid bf16 [B][23712]
// Vectorized epilogue: 16B stores (u16x8), float4 Wbil loads.
// ---------------------------------------------------------------------------
__global__ __launch_bounds__(256) void fuse_front(
    const int* __restrict__ cat, const float* __restrict__ num,
    const float* __restrict__ tables, const float* __restrict__ nemb,
    const float* __restrict__ Wse1, const float* __restrict__ Wse2,
    const float* __restrict__ Wbil, u16* __restrict__ hid)
{
  __shared__ float xs[NF][16];
  __shared__ float wb[NF][16][16];   // [f][e][d]
  __shared__ float pr[NF][16];       // proj
  __shared__ float Zs[NF], Ts[NNUM], As[NF];
  __shared__ unsigned char pis[NPAIR], pjs[NPAIR];

  const int b = blockIdx.x;
  const int tid = threadIdx.x;

  // Wbil: NF*256 f32 = 2560 float4
  for (int i = tid; i < NF * 64; i += 256)
    ((f32x4*)wb)[i] = ((const f32x4*)Wbil)[i];

  for (int t = tid; t < NNUM * 16; t += 256) {
    int f = t >> 4, e = t & 15;
    xs[f][e] = num[b * NNUM + f] * nemb[t];
  }
  for (int t = tid; t < NCAT * 16; t += 256) {
    int c = t >> 4, e = t & 15;
    int cv = cat[b * NCAT + c];
    xs[NNUM + c][e] = tables[((size_t)c * VOC + cv) * 16 + e];
  }
  for (int p = tid; p < NPAIR; p += 256) {
    int i = 0, rs = 0;
    while (p >= rs + (NF - 1 - i)) { rs += NF - 1 - i; ++i; }
    pis[p] = (unsigned char)i;
    pjs[p] = (unsigned char)(i + 1 + (p - rs));
  }
  __syncthreads();

  if (tid < NF) {
    float s = 0.f;
    #pragma unroll
    for (int e = 0; e < 16; ++e) s += xs[tid][e];
    Zs[tid] = s * (1.f / 16.f);
  }
  __syncthreads();
  if (tid < NNUM) {
    float s = 0.f;
    for (int f = 0; f < NF; ++f) s += Zs[f] * Wse1[f * NNUM + tid];
    Ts[tid] = fmaxf(s, 0.f);
  }
  __syncthreads();
  if (tid < NF) {
    float s = 0.f;
    for (int r = 0; r < NNUM; ++r) s += Ts[r] * Wse2[r * NF + tid];
    As[tid] = fmaxf(s, 0.f);
  }
  for (int t = tid; t < NF * 16; t += 256) {
    int f = t >> 4, d = t & 15;
    float s = 0.f;
    #pragma unroll
    for (int e = 0; e < 16; ++e) s += xs[f][e] * wb[f][e][d];
    pr[f][d] = s;
  }
  __syncthreads();

  // epilogue: 2 pairs-halves per iter, 16B stores
  u16* hr = hid + (size_t)b * KHID;
  for (int idx2 = tid; idx2 < NPAIR * 2; idx2 += 256) {
    const int p = idx2 >> 1, e0 = (idx2 & 1) * 8;
    const int i = pis[p], j = pjs[p];
    const float aa = As[i] * As[j];
    u16x8 vb, vs;
    #pragma unroll
    for (int e = 0; e < 8; ++e) {
      float bv = pr[i][e0 + e] * xs[j][e0 + e];
      vb[e] = f2bf(bv);
      vs[e] = f2bf(aa * bv);
    }
    *reinterpret_cast<u16x8*>(hr + NPAIR * 16 + p * 16 + e0) = vb;
    *reinterpret_cast<u16x8*>(hr + p * 16 + e0) = vs;
  }
}

// ---------------------------------------------------------------------------
// Merged transpose+cast for all three weight matrices, one launch.
// f32 [K][N] -> bf16 [N][K]; 32x32 tiles; 8B packed stores.
// ---------------------------------------------------------------------------
__global__ __launch_bounds__(256) void transpose_all(
    const float* __restrict__ Wd1, const float* __restrict__ Wd2,
    const float* __restrict__ Wd3, u16* __restrict__ W1t,
    u16* __restrict__ W2t, u16* __restrict__ W3t)
{
  __shared__ float t[32][33];
  const int bid = blockIdx.x;
  const float* in; u16* out; int K, N, kb, nb;
  if (bid < 741 * 32)        { in = Wd1; out = W1t; K = KHID; N = HD1; kb = bid % 741; nb = bid / 741; }
  else if (bid < 741 * 32 + 512) { int r = bid - 741 * 32; in = Wd2; out = W2t; K = HD1; N = HD2; kb = r % 32; nb = r / 32; }
  else                       { int r = bid - 741 * 32 - 512; in = Wd3; out = W3t; K = HD2; N = HD3; kb = r % 16; nb = r / 16; }

  const int k0 = kb * 32, n0 = nb * 32;
  const int c = threadIdx.x & 31, r = threadIdx.x >> 5;
  #pragma unroll
  for (int it = 0; it < 4; ++it)
    t[r + it * 8][c] = in[(size_t)(k0 + r + it * 8) * N + n0 + c];
  __syncthreads();
  // store: n = tid>>3 (32 rows), kq = (tid&7)*4 -> 8B packed
  const int n = threadIdx.x >> 3, kq = (threadIdx.x & 7) * 4;
  u16x4 v;
  #pragma unroll
  for (int q = 0; q < 4; ++q) v[q] = f2bf(t[kq + q][n]);
  *reinterpret_cast<u16x4*>(out + (size_t)(n0 + n) * K + k0 + kq) = v;
}

// ---------------------------------------------------------------------------
// 256x256 8-wave m201-style fine-phase GEMM (round-8 proven, untouched).
// ---------------------------------------------------------------------------
__global__ __launch_bounds__(512, 2) void gemm8p_bf16(
    const u16* __restrict__ A, const u16* __restrict__ Bt,
    float* __restrict__ Cp, int M, int N, int K, int totku, int kpb)
{
  __shared__ __align__(16) u16 lds[65536];   // 128 KiB: A slots @0, B slots @32768

  const int tid = threadIdx.x;
  const int wid = tid >> 6, lane = tid & 63;

  const int d = blockIdx.x;
  const int x = d & 7, jj = d >> 3;
  const int mb = ((x & 3) << 2) | (jj & 3);
  const int nb = (jj >> 2) & 3;
  const int sb = ((x >> 2) << 1) | (jj >> 4);

  const int ks0 = sb * kpb;
  const int kunits = (totku - ks0 < kpb) ? (totku - ks0) : kpb;
  const int ftiles = kunits >> 1;

  const int wm = wid >> 2, wn = wid & 3;
  const int lrow = lane & 15, c0 = lane >> 4;

  const int rr = tid >> 2, cc = tid & 3, csrc = cc ^ ((rr >> 1) & 3);
  const u16* pAg = A  + (size_t)((size_t)mb * 256 + rr) * K + (size_t)ks0 * 32 + csrc * 8;
  const u16* pBg = Bt + (size_t)((size_t)nb * 256 + rr) * K + (size_t)ks0 * 32 + csrc * 8;
  const size_t rsk = (size_t)128 * K;
  const int dstoff = tid * 8;

  int offA[8], offB[4];
  #pragma unroll
  for (int m = 0; m < 8; ++m) {
    int r = wm * 128 + m * 16 + lrow;
    offA[m] = r * 32 + ((c0 ^ ((r >> 1) & 3)) << 3);
  }
  #pragma unroll
  for (int n = 0; n < 4; ++n) {
    int r = wn * 64 + n * 16 + lrow;
    offB[n] = r * 32 + ((c0 ^ ((r >> 1) & 3)) << 3);
  }

#define STAGE_A(g) { int sg = ((g) < kunits) ? (g) : (kunits - 1);          \
    const u16* s_ = pAg + (size_t)sg * 32;                                   \
    u16* dp_ = lds + (((g) & 3) * 8192) + dstoff;                            \
    gload16(s_, dp_); gload16(s_ + rsk, dp_ + 4096); }
#define STAGE_B(g) { int sg = ((g) < kunits) ? (g) : (kunits - 1);          \
    const u16* s_ = pBg + (size_t)sg * 32;                                   \
    u16* dp_ = lds + 32768 + (((g) & 3) * 8192) + dstoff;                    \
    gload16(s_, dp_); gload16(s_ + rsk, dp_ + 4096); }

  f32x4 acc[8][4];
  #pragma unroll
  for (int m = 0; m < 8; ++m)
    #pragma unroll
    for (int n = 0; n < 4; ++n) acc[m][n] = f32x4{0.f, 0.f, 0.f, 0.f};

  STAGE_A(0); STAGE_B(0); STAGE_A(1); STAGE_B(1); STAGE_A(2); STAGE_B(2); STAGE_B(3);
  asm volatile("s_waitcnt vmcnt(10)" ::: "memory");
  __builtin_amdgcn_s_barrier();

  bf16x8 a0, a1, a2, a3, bg0, bg1, bg2, bg3;

  for (int tt = 0; tt < ftiles; ++tt) {
    const int g0 = tt << 1;
    const u16* As0 = lds + ((g0 & 3) * 8192);
    const u16* As1 = lds + (((g0 + 1) & 3) * 8192);
    const u16* Bs0 = lds + 32768 + ((g0 & 3) * 8192);
    const u16* Bs1 = lds + 32768 + (((g0 + 1) & 3) * 8192);

    // ---- P0
    a0 = *reinterpret_cast<const bf16x8*>(As0 + offA[0]);
    a1 = *reinterpret_cast<const bf16x8*>(As0 + offA[1]);
    a2 = *reinterpret_cast<const bf16x8*>(As0 + offA[2]);
    a3 = *reinterpret_cast<const bf16x8*>(As0 + offA[3]);
    bg0 = *reinterpret_cast<const bf16x8*>(Bs0 + offB[0]);
    bg1 = *reinterpret_cast<const bf16x8*>(Bs0 + offB[1]);
    bg2 = *reinterpret_cast<const bf16x8*>(Bs0 + offB[2]);
    bg3 = *reinterpret_cast<const bf16x8*>(Bs0 + offB[3]);
    STAGE_A(g0 + 3);
    __builtin_amdgcn_sched_barrier(0);
    __builtin_amdgcn_s_barrier();
    asm volatile("s_waitcnt lgkmcnt(0)" ::: "memory");
    __builtin_amdgcn_sched_barrier(0);
    __builtin_amdgcn_s_setprio(1);
    acc[0][0] = __builtin_amdgcn_mfma_f32_16x16x32_bf16(a0, bg0, acc[0][0], 0, 0, 0);
    acc[0][1] = __builtin_amdgcn_mfma_f32_16x16x32_bf16(a0, bg1, acc[0][1], 0, 0, 0);
    acc[0][2] = __builtin_amdgcn_mfma_f32_16x16x32_bf16(a0, bg2, acc[0][2], 0, 0, 0);
    acc[0][3] = __builtin_amdgcn_mfma_f32_16x16x32_bf16(a0, bg3, acc[0][3], 0, 0, 0);
    acc[1][0] = __builtin_amdgcn_mfma_f32_16x16x32_bf16(a1, bg0, acc[1][0], 0, 0, 0);
    acc[1][1] = __builtin_amdgcn_mfma_f32_16x16x32_bf16(a1, bg1, acc[1][1], 0, 0, 0);
    acc[1][2] = __builtin_amdgcn_mfma_f32_16x16x32_bf16(a1, bg2, acc[1][2], 0, 0, 0);
    acc[1][3] = __builtin_amdgcn_mfma_f32_16x16x32_bf16(a1, bg3, acc[1][3], 0, 0, 0);
    acc[2][0] = __builtin_amdgcn_mfma_f32_16x16x32_bf16(a2, bg0, acc[2][0], 0, 0, 0);
    acc[2][1] = __builtin_amdgcn_mfma_f32_16x16x32_bf16(a2, bg1, acc[2][1], 0, 0, 0);
    acc[2][2] = __builtin_amdgcn_mfma_f32_16x16x32_bf16(a2, bg2, acc[2][2], 0, 0, 0);
    acc[2][3] = __builtin_amdgcn_mfma_f32_16x16x32_bf16(a2, bg3, acc[2][3], 0, 0, 0);
    acc[3][0] = __builtin_amdgcn_mfma_f32_16x16x32_bf16(a3, bg0, acc[3][0], 0, 0, 0);
    acc[3][1] = __builtin_amdgcn_mfma_f32_16x16x32_bf16(a3, bg1, acc[3][1], 0, 0, 0);
    acc[3][2] = __builtin_amdgcn_mfma_f32_16x16x32_bf16(a3, bg2, acc[3][2], 0, 0, 0);
    acc[3][3] = __builtin_amdgcn_mfma_f32_16x16x32_bf16(a3, bg3, acc[3][3], 0, 0, 0);
    __builtin_amdgcn_s_setprio(0);
    __builtin_amdgcn_sched_barrier(0);
    __builtin_amdgcn_s_barrier();

    // ---- P1
    a0 = *reinterpret_cast<const bf16x8*>(As0 + offA[4]);
    a1 = *reinterpret_cast<const bf16x8*>(As0 + offA[5]);
    a2 = *reinterpret_cast<const bf16x8*>(As0 + offA[6]);
    a3 = *reinterpret_cast<const bf16x8*>(As0 + offA[7]);
    STAGE_B(g0 + 4);
    __builtin_amdgcn_sched_barrier(0);
    __builtin_amdgcn_s_barrier();
    asm volatile("s_waitcnt lgkmcnt(0)" ::: "memory");
    __builtin_amdgcn_sched_barrier(0);
    __builtin_amdgcn_s_setprio(1);
    acc[4][0] = __builtin_amdgcn_mfma_f32_16x16x32_bf16(a0, bg0, acc[4][0], 0, 0, 0);
    acc[4][1] = __builtin_amdgcn_mfma_f32_16x16x32_bf16(a0, bg1, acc[4][1], 0, 0, 0);
    acc[4][2] = __builtin_amdgcn_mfma_f32_16x16x32_bf16(a0, bg2, acc[4][2], 0, 0, 0);
    acc[4][3] = __builtin_amdgcn_mfma_f32_16x16x32_bf16(a0, bg3, acc[4][3], 0, 0, 0);
    acc[5][0] = __builtin_amdgcn_mfma_f32_16x16x32_bf16(a1, bg0, acc[5][0], 0, 0, 0);
    acc[5][1] = __builtin_amdgcn_mfma_f32_16x16x32_bf16(a1, bg1, acc[5][1], 0, 0, 0);
    acc[5][2] = __builtin_amdgcn_mfma_f32_16x16x32_bf16(a1, bg2, acc[5][2], 0, 0, 0);
    acc[5][3] = __builtin_amdgcn_mfma_f32_16x16x32_bf16(a1, bg3, acc[5][3], 0, 0, 0);
    acc[6][0] = __builtin_amdgcn_mfma_f32_16x16x32_bf16(a2, bg0, acc[6][0], 0, 0, 0);
    acc[6][1] = __builtin_amdgcn_mfma_f32_16x16x32_bf16(a2, bg1, acc[6][1], 0, 0, 0);
    acc[6][2] = __builtin_amdgcn_mfma_f32_16x16x32_bf16(a2, bg2, acc[6][2], 0, 0, 0);
    acc[6][3] = __builtin_amdgcn_mfma_f32_16x16x32_bf16(a2, bg3, acc[6][3], 0, 0, 0);
    acc[7][0] = __builtin_amdgcn_mfma_f32_16x16x32_bf16(a3, bg0, acc[7][0], 0, 0, 0);
    acc[7][1] = __builtin_amdgcn_mfma_f32_16x16x32_bf16(a3, bg1, acc[7][1], 0, 0, 0);
    acc[7][2] = __builtin_amdgcn_mfma_f32_16x16x32_bf16(a3, bg2, acc[7][2], 0, 0, 0);
    acc[7][3] = __builtin_amdgcn_mfma_f32_16x16x32_bf16(a3, bg3, acc[7][3], 0, 0, 0);
    __builtin_amdgcn_s_setprio(0);
    __builtin_amdgcn_sched_barrier(0);
    asm volatile("s_waitcnt vmcnt(8)" ::: "memory");
    __builtin_amdgcn_s_barrier();

    // ---- P2
    a0 = *reinterpret_cast<const bf16x8*>(As1 + offA[0]);
    a1 = *reinterpret_cast<const bf16x8*>(As1 + offA[1]);
    a2 = *reinterpret_cast<const bf16x8*>(As1 + offA[2]);
    a3 = *reinterpret_cast<const bf16x8*>(As1 + offA[3]);
    bg0 = *reinterpret_cast<const bf16x8*>(Bs1 + offB[0]);
    bg1 = *reinterpret_cast<const bf16x8*>(Bs1 + offB[1]);
    bg2 = *reinterpret_cast<const bf16x8*>(Bs1 + offB[2]);
    bg3 = *reinterpret_cast<const bf16x8*>(Bs1 + offB[3]);
    STAGE_A(g0 + 4);
    __builtin_amdgcn_sched_barrier(0);
    __builtin_amdgcn_s_barrier();
    asm volatile("s_waitcnt lgkmcnt(0)" ::: "memory");
    __builtin_amdgcn_sched_barrier(0);
    __builtin_amdgcn_s_setprio(1);
    acc[0][0] = __builtin_amdgcn_mfma_f32_16x16x32_bf16(a0, bg0, acc[0][0], 0, 0, 0);
    acc[0][1] = __builtin_amdgcn_mfma_f32_16x16x32_bf16(a0, bg1, acc[0][1], 0, 0, 0);
    acc[0][2] = __builtin_amdgcn_mfma_f32_16x16x32_bf16(a0, bg2, acc[0][2], 0, 0, 0);
    acc[0][3] = __builtin_amdgcn_mfma_f32_16x16x32_bf16(a0, bg3, acc[0][3], 0, 0, 0);
    acc[1][0] = __builtin_amdgcn_mfma_f32_16x16x32_bf16(a1, bg0, acc[1][0], 0, 0, 0);
    acc[1][1] = __builtin_amdgcn_mfma_f32_16x16x32_bf16(a1, bg1, acc[1][1], 0, 0, 0);
    acc[1][2] = __builtin_amdgcn_mfma_f32_16x16x32_bf16(a1, bg2, acc[1][2], 0, 0, 0);
    acc[1][3] = __builtin_amdgcn_mfma_f32_16x16x32_bf16(a1, bg3, acc[1][3], 0, 0, 0);
    acc[2][0] = __builtin_amdgcn_mfma_f32_16x16x32_bf16(a2, bg0, acc[2][0], 0, 0, 0);
    acc[2][1] = __builtin_amdgcn_mfma_f32_16x16x32_bf16(a2, bg1, acc[2][1], 0, 0, 0);
    acc[2][2] = __builtin_amdgcn_mfma_f32_16x16x32_bf16(a2, bg2, acc[2][2], 0, 0, 0);
    acc[2][3] = __builtin_amdgcn_mfma_f32_16x16x32_bf16(a2, bg3, acc[2][3], 0, 0, 0);
    acc[3][0] = __builtin_amdgcn_mfma_f32_16x16x32_bf16(a3, bg0, acc[3][0], 0, 0, 0);
    acc[3][1] = __builtin_amdgcn_mfma_f32_16x16x32_bf16(a3, bg1, acc[3][1], 0, 0, 0);
    acc[3][2] = __builtin_amdgcn_mfma_f32_16x16x32_bf16(a3, bg2, acc[3][2], 0, 0, 0);
    acc[3][3] = __builtin_amdgcn_mfma_f32_16x16x32_bf16(a3, bg3, acc[3][3], 0, 0, 0);
    __builtin_amdgcn_s_setprio(0);
    __builtin_amdgcn_sched_barrier(0);
    __builtin_amdgcn_s_barrier();

    // ---- P3
    a0 = *reinterpret_cast<const bf16x8*>(As1 + offA[4]);
    a1 = *reinterpret_cast<const bf16x8*>(As1 + offA[5]);
    a2 = *reinterpret_cast<const bf16x8*>(As1 + offA[6]);
    a3 = *reinterpret_cast<const bf16x8*>(As1 + offA[7]);
    STAGE_B(g0 + 5);
    __builtin_amdgcn_sched_barrier(0);
    __builtin_amdgcn_s_barrier();
    asm volatile("s_waitcnt lgkmcnt(0)" ::: "memory");
    __builtin_amdgcn_sched_barrier(0);
    __builtin_amdgcn_s_setprio(1);
    acc[4][0] = __builtin_amdgcn_mfma_f32_16x16x32_bf16(a0, bg0, acc[4][0], 0, 0, 0);
    acc[4][1] = __builtin_amdgcn_mfma_f32_16x16x32_bf16(a0, bg1, acc[4][1], 0, 0, 0);
    acc[4][2] = __builtin_amdgcn_mfma_f32_16x16x32_bf16(a0, bg2, acc[4][2], 0, 0, 0);
    acc[4][3] = __builtin_amdgcn_mfma_f32_16x16x32_bf16(a0, bg3, acc[4][3], 0, 0, 0);
    acc[5][0] = __builtin_amdgcn_mfma_f32_16x16x32_bf16(a1, bg0, acc[5][0], 0, 0, 0);
    acc[5][1] = __builtin_amdgcn_mfma_f32_16x16x32_bf16(a1, bg1, acc[5][1], 0, 0, 0);
    acc[5][2] = __builtin_amdgcn_mfma_f32_16x16x32_bf16(a1, bg2, acc[5][2], 0, 0, 0);
    acc[5][3] = __builtin_amdgcn_mfma_f32_16x16x32_bf16(a1, bg3, acc[5][3], 0, 0, 0);
    acc[6][0] = __builtin_amdgcn_mfma_f32_16x16x32_bf16(a2, bg0, acc[6][0], 0, 0, 0);
    acc[6][1] = __builtin_amdgcn_mfma_f32_16x16x32_bf16(a2, bg1, acc[6][1], 0, 0, 0);
    acc[6][2] = __builtin_amdgcn_mfma_f32_16x16x32_bf16(a2, bg2, acc[6][2], 0, 0, 0);
    acc[6][3] = __builtin_amdgcn_mfma_f32_16x16x32_bf16(a2, bg3, acc[6][3], 0, 0, 0);
    acc[7][0] = __builtin_amdgcn_mfma_f32_16x16x32_bf16(a3, bg0, acc[7][0], 0, 0, 0);
    acc[7][1] = __builtin_amdgcn_mfma_f32_16x16x32_bf16(a3, bg1, acc[7][1], 0, 0, 0);
    acc[7][2] = __builtin_amdgcn_mfma_f32_16x16x32_bf16(a3, bg2, acc[7][2], 0, 0, 0);
    acc[7][3] = __builtin_amdgcn_mfma_f32_16x16x32_bf16(a3, bg3, acc[7][3], 0, 0, 0);
    __builtin_amdgcn_s_setprio(0);
    __builtin_amdgcn_sched_barrier(0);
    asm volatile("s_waitcnt vmcnt(8)" ::: "memory");
    __builtin_amdgcn_s_barrier();
  }

  if (kunits & 1) {
    asm volatile("s_waitcnt vmcnt(0)" ::: "memory");
    __builtin_amdgcn_s_barrier();
    const int g = kunits - 1;
    const u16* As = lds + ((g & 3) * 8192);
    const u16* Bs = lds + 32768 + ((g & 3) * 8192);
    bg0 = *reinterpret_cast<const bf16x8*>(Bs + offB[0]);
    bg1 = *reinterpret_cast<const bf16x8*>(Bs + offB[1]);
    bg2 = *reinterpret_cast<const bf16x8*>(Bs + offB[2]);
    bg3 = *reinterpret_cast<const bf16x8*>(Bs + offB[3]);
    #pragma unroll
    for (int m = 0; m < 8; ++m) {
      bf16x8 am = *reinterpret_cast<const bf16x8*>(As + offA[m]);
      acc[m][0] = __builtin_amdgcn_mfma_f32_16x16x32_bf16(am, bg0, acc[m][0], 0, 0, 0);
      acc[m][1] = __builtin_amdgcn_mfma_f32_16x16x32_bf16(am, bg1, acc[m][1], 0, 0, 0);
      acc[m][2] = __builtin_amdgcn_mfma_f32_16x16x32_bf16(am, bg2, acc[m][2], 0, 0, 0);
      acc[m][3] = __builtin_amdgcn_mfma_f32_16x16x32_bf16(am, bg3, acc[m][3], 0, 0, 0);
    }
  }
#undef STAGE_A
#undef STAGE_B

  float* C = Cp + (size_t)sb * M * N;
  #pragma unroll
  for (int m = 0; m < 8; ++m) {
    const int rb = mb * 256 + wm * 128 + m * 16 + (lane >> 4) * 4;
    #pragma unroll
    for (int n = 0; n < 4; ++n) {
      const int col = nb * 256 + wn * 64 + n * 16 + (lane & 15);
      #pragma unroll
      for (int j2 = 0; j2 < 4; ++j2)
        __builtin_nontemporal_store(acc[m][n][j2], &C[(size_t)(rb + j2) * N + col]);
    }
  }
}

// ---------------------------------------------------------------------------
// 128x128 m97-structure GEMM for the small layers 2/3
// ---------------------------------------------------------------------------
__global__ __launch_bounds__(256) void gemm_bf16(
    const u16* __restrict__ A, const u16* __restrict__ Bt,
    float* __restrict__ Cp, int M, int N, int K, int kps)
{
  __shared__ __align__(16) u16 lA[128 * 32];
  __shared__ __align__(16) u16 lB[128 * 32];
  const int tid = threadIdx.x;
  const int mb = blockIdx.x, nb = blockIdx.y, sb = blockIdx.z;
  const int w = tid >> 6, lane = tid & 63;
  const int wr = (w >> 1) * 64, wc = (w & 1) * 64;
  const int lrow = lane & 15, lko = (lane >> 4) * 8;

  f32x4 acc[4][4];
  #pragma unroll
  for (int m = 0; m < 4; ++m)
    #pragma unroll
    for (int n = 0; n < 4; ++n) acc[m][n] = f32x4{0.f, 0.f, 0.f, 0.f};

  const u16* Ab = A + (size_t)mb * 128 * K;
  const u16* Bb = Bt + (size_t)nb * 128 * K;
  const int r0 = tid >> 2, inn = (tid & 3) * 8;
  const int l0 = (tid & ~63) * 8, l1 = ((256 + tid) & ~63) * 8;

  const int ks1 = (sb + 1) * kps;
  for (int ks = sb * kps; ks < ks1; ++ks) {
    const int k0 = ks * 32;
    __syncthreads();
    gload16(Ab + (size_t)r0 * K + k0 + inn,        lA + l0);
    gload16(Ab + (size_t)(r0 + 64) * K + k0 + inn, lA + l1);
    gload16(Bb + (size_t)r0 * K + k0 + inn,        lB + l0);
    gload16(Bb + (size_t)(r0 + 64) * K + k0 + inn, lB + l1);
    __syncthreads();
    bf16x8 af[4], bg[4];
    #pragma unroll
    for (int m = 0; m < 4; ++m)
      af[m] = *reinterpret_cast<const bf16x8*>(&lA[(wr + m * 16 + lrow) * 32 + lko]);
    #pragma unroll
    for (int n = 0; n < 4; ++n)
      bg[n] = *reinterpret_cast<const bf16x8*>(&lB[(wc + n * 16 + lrow) * 32 + lko]);
    #pragma unroll
    for (int m = 0; m < 4; ++m)
      #pragma unroll
      for (int n = 0; n < 4; ++n)
        acc[m][n] = __builtin_amdgcn_mfma_f32_16x16x32_bf16(af[m], bg[n], acc[m][n], 0, 0, 0);
  }

  float* C = Cp + (size_t)sb * M * N;
  #pragma unroll
  for (int m = 0; m < 4; ++m) {
    const int rb = mb * 128 + wr + m * 16 + (lane >> 4) * 4;
    #pragma unroll
    for (int n = 0; n < 4; ++n) {
      const int col = nb * 128 + wc + n * 16 + (lane & 15);
      #pragma unroll
      for (int j = 0; j < 4; ++j)
        __builtin_nontemporal_store(acc[m][n][j], &C[(size_t)(rb + j) * N + col]);
    }
  }
}

// ---------------------------------------------------------------------------
// Split-K reduce + bias + relu, vectorized: f32x4 NT loads, 16B stores.
// Processes 8 outputs/thread. MN must be a multiple of 8 (it is).
// ---------------------------------------------------------------------------
__global__ __launch_bounds__(256) void reduce_bias_relu_bf16(
    const float* __restrict__ part, int S, size_t MN,
    const float* __restrict__ bias, int nmask, u16* __restrict__ out)
{
  const size_t n8 = MN >> 3;
  for (size_t i8 = blockIdx.x * 256ull + threadIdx.x; i8 < n8; i8 += (size_t)gridDim.x * 256) {
    const size_t base = i8 * 8;
    f32x4 lo = {0.f, 0.f, 0.f, 0.f}, hi = {0.f, 0.f, 0.f, 0.f};
    for (int k = 0; k < S; ++k) {
      const float* p = part + (size_t)k * MN + base;
      f32x4 a = __builtin_nontemporal_load(reinterpret_cast<const f32x4*>(p));
      f32x4 b = __builtin_nontemporal_load(reinterpret_cast<const f32x4*>(p + 4));
      lo += a; hi += b;
    }
    const int bb = (int)(base & (size_t)nmask);
    const f32x4 b0 = *reinterpret_cast<const f32x4*>(bias + bb);
    const f32x4 b1 = *reinterpret_cast<const f32x4*>(bias + bb + 4);
    u16x8 v;
    #pragma unroll
    for (int e = 0; e < 4; ++e) v[e] = f2bf(fmaxf(lo[e] + b0[e], 0.f));
    #pragma unroll
    for (int e = 0; e < 4; ++e) v[4 + e] = f2bf(fmaxf(hi[e] + b1[e], 0.f));
    *reinterpret_cast<u16x8*>(out + base) = v;
  }
}

__global__ __launch_bounds__(256) void reduce_bias_relu_f32(
    const float* __restrict__ part, int S, size_t MN,
    const float* __restrict__ bias, int nmask, float* __restrict__ out)
{
  const size_t n8 = MN >> 3;
  for (size_t i8 = blockIdx.x * 256ull + threadIdx.x; i8 < n8; i8 += (size_t)gridDim.x * 256) {
    const size_t base = i8 * 8;
    f32x4 lo = {0.f, 0.f, 0.f, 0.f}, hi = {0.f, 0.f, 0.f, 0.f};
    for (int k = 0; k < S; ++k) {
      const float* p = part + (size_t)k * MN + base;
      f32x4 a = __builtin_nontemporal_load(reinterpret_cast<const f32x4*>(p));
      f32x4 b = __builtin_nontemporal_load(reinterpret_cast<const f32x4*>(p + 4));
      lo += a; hi += b;
    }
    const int bb = (int)(base & (size_t)nmask);
    const f32x4 b0 = *reinterpret_cast<const f32x4*>(bias + bb);
    const f32x4 b1 = *reinterpret_cast<const f32x4*>(bias + bb + 4);
    f32x4 o0, o1;
    #pragma unroll
    for (int e = 0; e < 4; ++e) { o0[e] = fmaxf(lo[e] + b0[e], 0.f); o1[e] = fmaxf(hi[e] + b1[e], 0.f); }
    *reinterpret_cast<f32x4*>(out + base) = o0;
    *reinterpret_cast<f32x4*>(out + base + 4) = o1;
  }
}

// ---------------------------------------------------------------------------
// Final: out[b] = h3[b,:] . W_out + b_out   (one wave per row)
// ---------------------------------------------------------------------------
__global__ __launch_bounds__(256) void final_dot(
    const float* __restrict__ h3, const float* __restrict__ Wout,
    const float* __restrict__ bout, float* __restrict__ out)
{
  const int row = blockIdx.x * 4 + (threadIdx.x >> 6);
  const int lane = threadIdx.x & 63;
  const float* hr = h3 + (size_t)row * HD3;
  float s = 0.f;
  #pragma unroll
  for (int i = 0; i < 4; ++i) s += hr[lane + i * 64] * Wout[lane + i * 64];
  #pragma unroll
  for (int off = 32; off; off >>= 1) s += __shfl_down(s, off, 64);
  if (lane == 0) out[row] = s + bout[0];
}

// ---------------------------------------------------------------------------
extern "C" void kernel_launch(void* const* d_in, const int* in_sizes, int n_in,
                              void* d_out, int out_size, void* d_ws, size_t ws_size,
                              hipStream_t stream)
{
  const int*   cat    = (const int*)  d_in[0];
  const float* num    = (const float*)d_in[1];
  const float* tables = (const float*)d_in[2];
  const float* nemb   = (const float*)d_in[3];
  const float* Wse1   = (const float*)d_in[4];
  const float* Wse2   = (const float*)d_in[5];
  const float* Wbil   = (const float*)d_in[6];
  const float* Wd1    = (const float*)d_in[7];
  const float* bd1    = (const float*)d_in[8];
  const float* Wd2    = (const float*)d_in[9];
  const float* bd2    = (const float*)d_in[10];
  const float* Wd3    = (const float*)d_in[11];
  const float* bd3    = (const float*)d_in[12];
  const float* Wout   = (const float*)d_in[13];
  const float* bout   = (const float*)d_in[14];

  char* ws = (char*)d_ws;
  // ws layout (total 311,230,464 B — round-3 proven footprint):
  u16*   hid  = (u16*)  (ws + 0ull);           // 194,248,704  bf16 [4096][23712]
  u16*   W1t  = (u16*)  (ws + 194248704ull);   //  48,562,176  bf16 [1024][23712]
  float* part = (float*)(ws + 242810880ull);   //  67,108,864  f32 splitK partials (S<=4)
  u16*   W2t  = (u16*)  (ws + 309919744ull);   //   1,048,576  bf16 [512][1024]
  u16*   W3t  = (u16*)  (ws + 310968320ull);   //     262,144  bf16 [256][512]
  // dead-hid region reuse (hid consumed by gemm1 before these are written):
  u16*   h1b  = (u16*)  (ws + 0ull);           //   8,388,608  bf16 [4096][1024]
  u16*   h2b  = (u16*)  (ws + 8388608ull);     //   4,194,304  bf16 [4096][512]
  float* h3f  = (float*)(ws + 12582912ull);    //   4,194,304  f32  [4096][256]

  // all three weight transposes in one launch: 741*32 + 512 + 128 blocks
  transpose_all<<<741 * 32 + 512 + 128, 256, 0, stream>>>(Wd1, Wd2, Wd3, W1t, W2t, W3t);
  fuse_front<<<BATCH, 256, 0, stream>>>(cat, num, tables, nemb, Wse1, Wse2, Wbil, hid);

  // layer 1: [4096 x 23712] @ [23712 x 1024], 256^2 fine-phase pipelined,
  // split-K=4 uneven (186/186/186/183 units of 32), 1D grid 256 = exact CU fill
  gemm8p_bf16<<<256, 512, 0, stream>>>(hid, W1t, part, BATCH, HD1, KHID, 741, 186);
  reduce_bias_relu_bf16<<<2048, 256, 0, stream>>>(part, 4, (size_t)BATCH * HD1, bd1, HD1 - 1, h1b);

  // layer 2: [4096 x 1024] @ [1024 x 512], split-K=2 (32 = 2*16)
  gemm_bf16<<<dim3(BATCH / 128, HD2 / 128, 2), 256, 0, stream>>>(h1b, W2t, part, BATCH, HD2, HD1, 16);
  reduce_bias_relu_bf16<<<1024, 256, 0, stream>>>(part, 2, (size_t)BATCH * HD2, bd2, HD2 - 1, h2b);

  // layer 3: [4096 x 512] @ [512 x 256], split-K=4 (16 = 4*4)
  gemm_bf16<<<dim3(BATCH / 128, HD3 / 128, 4), 256, 0, stream>>>(h2b, W3t, part, BATCH, HD3, HD2, 4);
  reduce_bias_relu_f32<<<512, 256, 0, stream>>>(part, 4, (size_t)BATCH * HD3, bd3, HD3 - 1, h3f);

  final_dot<<<BATCH / 4, 256, 0, stream>>>(h3f, Wout, bout, (float*)d_out);
}

// Round 10
// 332.115 us; speedup vs baseline: 1.1563x; 1.0333x over previous
//
#include <hip/hip_runtime.h>

typedef unsigned short u16;
typedef __attribute__((ext_vector_type(8))) __bf16 bf16x8;
typedef __attribute__((ext_vector_type(4))) float f32x4;
typedef __attribute__((ext_vector_type(4))) unsigned short u16x4;
typedef __attribute__((ext_vector_type(8))) unsigned short u16x8;

#define NF    39
#define NNUM  13
#define NCAT  26
#define VOC   100000
#define NPAIR 741
#define KHID  23712   /* 2*741*16 */
#define BATCH 4096
#define HD1   1024
#define HD2   512
#define HD3   256

__device__ __forceinline__ u16 f2bf(float f) {
  unsigned u = __builtin_bit_cast(unsigned, f);
  return (u16)((u + 0x7fffu + ((u >> 16) & 1u)) >> 16);   // RNE
}

__device__ __forceinline__ void gload16(const void* g, void* l) {
  __builtin_amdgcn_global_load_lds((const __attribute__((address_space(1))) void*)g,
                                   (__attribute__((address_space(3))) void*)l, 16, 0, 0);
}

// ---------------------------------------------------------------------------
// Front end, 2 rows per block: gather + SE + bilinear + pair products
// -> hid bf16 [B][23712]. Per-row FP order identical to the 1-row version.
// ---------------------------------------------------------------------------
__global__ __launch_bounds__(256) void fuse_front(
    const int* __restrict__ cat, const float* __restrict__ num,
    const float* __restrict__ tables, const float* __restrict__ nemb,
    const float* __restrict__ Wse1, const float* __restrict__ Wse2,
    const float* __restrict__ Wbil, u16* __restrict__ hid)
{
  __shared__ float xs[2][NF][16];
  __shared__ float wb[NF][16][16];   // [f][e][d]
  __shared__ float pr[2][NF][16];
  __shared__ float Zs[2][NF], Ts[2][NNUM], As[2][NF];
  __shared__ unsigned char pis[NPAIR], pjs[NPAIR];

  const int b0 = blockIdx.x * 2;
  const int tid = threadIdx.x;

  for (int i = tid; i < NF * 64; i += 256)
    ((f32x4*)wb)[i] = ((const f32x4*)Wbil)[i];

  for (int t = tid; t < 2 * NNUM * 16; t += 256) {
    int r = t / (NNUM * 16), t2 = t % (NNUM * 16);
    int f = t2 >> 4, e = t2 & 15;
    xs[r][f][e] = num[(b0 + r) * NNUM + f] * nemb[t2];
  }
  for (int t = tid; t < 2 * NCAT * 16; t += 256) {
    int r = t / (NCAT * 16), t2 = t % (NCAT * 16);
    int c = t2 >> 4, e = t2 & 15;
    int cv = cat[(b0 + r) * NCAT + c];
    xs[r][NNUM + c][e] = tables[((size_t)c * VOC + cv) * 16 + e];
  }
  for (int p = tid; p < NPAIR; p += 256) {
    int i = 0, rs = 0;
    while (p >= rs + (NF - 1 - i)) { rs += NF - 1 - i; ++i; }
    pis[p] = (unsigned char)i;
    pjs[p] = (unsigned char)(i + 1 + (p - rs));
  }
  __syncthreads();

  if (tid < 2 * NF) {
    int r = tid / NF, f = tid % NF;
    float s = 0.f;
    #pragma unroll
    for (int e = 0; e < 16; ++e) s += xs[r][f][e];
    Zs[r][f] = s * (1.f / 16.f);
  }
  __syncthreads();
  if (tid < 2 * NNUM) {
    int r = tid / NNUM, o = tid % NNUM;
    float s = 0.f;
    for (int f = 0; f < NF; ++f) s += Zs[r][f] * Wse1[f * NNUM + o];
    Ts[r][o] = fmaxf(s, 0.f);
  }
  __syncthreads();
  if (tid < 2 * NF) {
    int r = tid / NF, f = tid % NF;
    float s = 0.f;
    for (int q = 0; q < NNUM; ++q) s += Ts[r][q] * Wse2[q * NF + f];
    As[r][f] = fmaxf(s, 0.f);
  }
  for (int t = tid; t < 2 * NF * 16; t += 256) {
    int r = t / (NF * 16), t2 = t % (NF * 16);
    int f = t2 >> 4, d = t2 & 15;
    float s = 0.f;
    #pragma unroll
    for (int e = 0; e < 16; ++e) s += xs[r][f][e] * wb[f][e][d];
    pr[r][f][d] = s;
  }
  __syncthreads();

  for (int idx = tid; idx < 2 * NPAIR * 2; idx += 256) {
    const int r = idx / (NPAIR * 2), idx2 = idx % (NPAIR * 2);
    const int p = idx2 >> 1, e0 = (idx2 & 1) * 8;
    const int i = pis[p], j = pjs[p];
    const float aa = As[r][i] * As[r][j];
    u16* hr = hid + (size_t)(b0 + r) * KHID;
    u16x8 vb, vs;
    #pragma unroll
    for (int e = 0; e < 8; ++e) {
      float bv = pr[r][i][e0 + e] * xs[r][j][e0 + e];
      vb[e] = f2bf(bv);
      vs[e] = f2bf(aa * bv);
    }
    *reinterpret_cast<u16x8*>(hr + NPAIR * 16 + p * 16 + e0) = vb;
    *reinterpret_cast<u16x8*>(hr + p * 16 + e0) = vs;
  }
}

// ---------------------------------------------------------------------------
// Merged transpose+cast for all three weight matrices, one launch.
// ---------------------------------------------------------------------------
__global__ __launch_bounds__(256) void transpose_all(
    const float* __restrict__ Wd1, const float* __restrict__ Wd2,
    const float* __restrict__ Wd3, u16* __restrict__ W1t,
    u16* __restrict__ W2t, u16* __restrict__ W3t)
{
  __shared__ float t[32][33];
  const int bid = blockIdx.x;
  const float* in; u16* out; int K, N, kb, nb;
  if (bid < 741 * 32)        { in = Wd1; out = W1t; K = KHID; N = HD1; kb = bid % 741; nb = bid / 741; }
  else if (bid < 741 * 32 + 512) { int r = bid - 741 * 32; in = Wd2; out = W2t; K = HD1; N = HD2; kb = r % 32; nb = r / 32; }
  else                       { int r = bid - 741 * 32 - 512; in = Wd3; out = W3t; K = HD2; N = HD3; kb = r % 16; nb = r / 16; }

  const int k0 = kb * 32, n0 = nb * 32;
  const int c = threadIdx.x & 31, r = threadIdx.x >> 5;
  #pragma unroll
  for (int it = 0; it < 4; ++it)
    t[r + it * 8][c] = in[(size_t)(k0 + r + it * 8) * N + n0 + c];
  __syncthreads();
  const int n = threadIdx.x >> 3, kq = (threadIdx.x & 7) * 4;
  u16x4 v;
  #pragma unroll
  for (int q = 0; q < 4; ++q) v[q] = f2bf(t[kq + q][n]);
  *reinterpret_cast<u16x4*>(out + (size_t)(n0 + n) * K + k0 + kq) = v;
}

// ---------------------------------------------------------------------------
// 256x256 8-wave fine-phase GEMM. Round-8 structure; this round: ONE counted
// vmcnt per K-tile (m201 pattern). Accounting (oldest-first): prologue
// vmcnt(6) forces A0,B0,A1,B1; each P3-end vmcnt(6) forces the 4 granules
// the NEXT tile reads (A/B of g0,g0+1). Slot write-after-read safety is
// barrier-carried (stage-issue >=1 phase after last read), unchanged.
// ---------------------------------------------------------------------------
__global__ __launch_bounds__(512, 2) void gemm8p_bf16(
    const u16* __restrict__ A, const u16* __restrict__ Bt,
    float* __restrict__ Cp, int M, int N, int K, int totku, int kpb)
{
  __shared__ __align__(16) u16 lds[65536];   // 128 KiB: A slots @0, B slots @32768

  const int tid = threadIdx.x;
  const int wid = tid >> 6, lane = tid & 63;

  const int d = blockIdx.x;
  const int x = d & 7, jj = d >> 3;
  const int mb = ((x & 3) << 2) | (jj & 3);
  const int nb = (jj >> 2) & 3;
  const int sb = ((x >> 2) << 1) | (jj >> 4);

  const int ks0 = sb * kpb;
  const int kunits = (totku - ks0 < kpb) ? (totku - ks0) : kpb;
  const int ftiles = kunits >> 1;

  const int wm = wid >> 2, wn = wid & 3;
  const int lrow = lane & 15, c0 = lane >> 4;

  const int rr = tid >> 2, cc = tid & 3, csrc = cc ^ ((rr >> 1) & 3);
  const u16* pAg = A  + (size_t)((size_t)mb * 256 + rr) * K + (size_t)ks0 * 32 + csrc * 8;
  const u16* pBg = Bt + (size_t)((size_t)nb * 256 + rr) * K + (size_t)ks0 * 32 + csrc * 8;
  const size_t rsk = (size_t)128 * K;
  const int dstoff = tid * 8;

  int offA[8], offB[4];
  #pragma unroll
  for (int m = 0; m < 8; ++m) {
    int r = wm * 128 + m * 16 + lrow;
    offA[m] = r * 32 + ((c0 ^ ((r >> 1) & 3)) << 3);
  }
  #pragma unroll
  for (int n = 0; n < 4; ++n) {
    int r = wn * 64 + n * 16 + lrow;
    offB[n] = r * 32 + ((c0 ^ ((r >> 1) & 3)) << 3);
  }

#define STAGE_A(g) { int sg = ((g) < kunits) ? (g) : (kunits - 1);          \
    const u16* s_ = pAg + (size_t)sg * 32;                                   \
    u16* dp_ = lds + (((g) & 3) * 8192) + dstoff;                            \
    gload16(s_, dp_); gload16(s_ + rsk, dp_ + 4096); }
#define STAGE_B(g) { int sg = ((g) < kunits) ? (g) : (kunits - 1);          \
    const u16* s_ = pBg + (size_t)sg * 32;                                   \
    u16* dp_ = lds + 32768 + (((g) & 3) * 8192) + dstoff;                    \
    gload16(s_, dp_); gload16(s_ + rsk, dp_ + 4096); }

  f32x4 acc[8][4];
  #pragma unroll
  for (int m = 0; m < 8; ++m)
    #pragma unroll
    for (int n = 0; n < 4; ++n) acc[m][n] = f32x4{0.f, 0.f, 0.f, 0.f};

  STAGE_A(0); STAGE_B(0); STAGE_A(1); STAGE_B(1); STAGE_A(2); STAGE_B(2); STAGE_B(3);
  asm volatile("s_waitcnt vmcnt(6)" ::: "memory");   // forces A0,B0,A1,B1
  __builtin_amdgcn_s_barrier();

  bf16x8 a0, a1, a2, a3, bg0, bg1, bg2, bg3;

  for (int tt = 0; tt < ftiles; ++tt) {
    const int g0 = tt << 1;
    const u16* As0 = lds + ((g0 & 3) * 8192);
    const u16* As1 = lds + (((g0 + 1) & 3) * 8192);
    const u16* Bs0 = lds + 32768 + ((g0 & 3) * 8192);
    const u16* Bs1 = lds + 32768 + (((g0 + 1) & 3) * 8192);

    // ---- P0: af(m0-3,kk0)+bg(kk0); stage A(g0+3)
    a0 = *reinterpret_cast<const bf16x8*>(As0 + offA[0]);
    a1 = *reinterpret_cast<const bf16x8*>(As0 + offA[1]);
    a2 = *reinterpret_cast<const bf16x8*>(As0 + offA[2]);
    a3 = *reinterpret_cast<const bf16x8*>(As0 + offA[3]);
    bg0 = *reinterpret_cast<const bf16x8*>(Bs0 + offB[0]);
    bg1 = *reinterpret_cast<const bf16x8*>(Bs0 + offB[1]);
    bg2 = *reinterpret_cast<const bf16x8*>(Bs0 + offB[2]);
    bg3 = *reinterpret_cast<const bf16x8*>(Bs0 + offB[3]);
    STAGE_A(g0 + 3);
    __builtin_amdgcn_sched_barrier(0);
    __builtin_amdgcn_s_barrier();
    asm volatile("s_waitcnt lgkmcnt(0)" ::: "memory");
    __builtin_amdgcn_sched_barrier(0);
    __builtin_amdgcn_s_setprio(1);
    acc[0][0] = __builtin_amdgcn_mfma_f32_16x16x32_bf16(a0, bg0, acc[0][0], 0, 0, 0);
    acc[0][1] = __builtin_amdgcn_mfma_f32_16x16x32_bf16(a0, bg1, acc[0][1], 0, 0, 0);
    acc[0][2] = __builtin_amdgcn_mfma_f32_16x16x32_bf16(a0, bg2, acc[0][2], 0, 0, 0);
    acc[0][3] = __builtin_amdgcn_mfma_f32_16x16x32_bf16(a0, bg3, acc[0][3], 0, 0, 0);
    acc[1][0] = __builtin_amdgcn_mfma_f32_16x16x32_bf16(a1, bg0, acc[1][0], 0, 0, 0);
    acc[1][1] = __builtin_amdgcn_mfma_f32_16x16x32_bf16(a1, bg1, acc[1][1], 0, 0, 0);
    acc[1][2] = __builtin_amdgcn_mfma_f32_16x16x32_bf16(a1, bg2, acc[1][2], 0, 0, 0);
    acc[1][3] = __builtin_amdgcn_mfma_f32_16x16x32_bf16(a1, bg3, acc[1][3], 0, 0, 0);
    acc[2][0] = __builtin_amdgcn_mfma_f32_16x16x32_bf16(a2, bg0, acc[2][0], 0, 0, 0);
    acc[2][1] = __builtin_amdgcn_mfma_f32_16x16x32_bf16(a2, bg1, acc[2][1], 0, 0, 0);
    acc[2][2] = __builtin_amdgcn_mfma_f32_16x16x32_bf16(a2, bg2, acc[2][2], 0, 0, 0);
    acc[2][3] = __builtin_amdgcn_mfma_f32_16x16x32_bf16(a2, bg3, acc[2][3], 0, 0, 0);
    acc[3][0] = __builtin_amdgcn_mfma_f32_16x16x32_bf16(a3, bg0, acc[3][0], 0, 0, 0);
    acc[3][1] = __builtin_amdgcn_mfma_f32_16x16x32_bf16(a3, bg1, acc[3][1], 0, 0, 0);
    acc[3][2] = __builtin_amdgcn_mfma_f32_16x16x32_bf16(a3, bg2, acc[3][2], 0, 0, 0);
    acc[3][3] = __builtin_amdgcn_mfma_f32_16x16x32_bf16(a3, bg3, acc[3][3], 0, 0, 0);
    __builtin_amdgcn_s_setprio(0);
    __builtin_amdgcn_sched_barrier(0);
    __builtin_amdgcn_s_barrier();

    // ---- P1: af(m4-7,kk0); stage B(g0+4); no vmcnt here
    a0 = *reinterpret_cast<const bf16x8*>(As0 + offA[4]);
    a1 = *reinterpret_cast<const bf16x8*>(As0 + offA[5]);
    a2 = *reinterpret_cast<const bf16x8*>(As0 + offA[6]);
    a3 = *reinterpret_cast<const bf16x8*>(As0 + offA[7]);
    STAGE_B(g0 + 4);
    __builtin_amdgcn_sched_barrier(0);
    __builtin_amdgcn_s_barrier();
    asm volatile("s_waitcnt lgkmcnt(0)" ::: "memory");
    __builtin_amdgcn_sched_barrier(0);
    __builtin_amdgcn_s_setprio(1);
    acc[4][0] = __builtin_amdgcn_mfma_f32_16x16x32_bf16(a0, bg0, acc[4][0], 0, 0, 0);
    acc[4][1] = __builtin_amdgcn_mfma_f32_16x16x32_bf16(a0, bg1, acc[4][1], 0, 0, 0);
    acc[4][2] = __builtin_amdgcn_mfma_f32_16x16x32_bf16(a0, bg2, acc[4][2], 0, 0, 0);
    acc[4][3] = __builtin_amdgcn_mfma_f32_16x16x32_bf16(a0, bg3, acc[4][3], 0, 0, 0);
    acc[5][0] = __builtin_amdgcn_mfma_f32_16x16x32_bf16(a1, bg0, acc[5][0], 0, 0, 0);
    acc[5][1] = __builtin_amdgcn_mfma_f32_16x16x32_bf16(a1, bg1, acc[5][1], 0, 0, 0);
    acc[5][2] = __builtin_amdgcn_mfma_f32_16x16x32_bf16(a1, bg2, acc[5][2], 0, 0, 0);
    acc[5][3] = __builtin_amdgcn_mfma_f32_16x16x32_bf16(a1, bg3, acc[5][3], 0, 0, 0);
    acc[6][0] = __builtin_amdgcn_mfma_f32_16x16x32_bf16(a2, bg0, acc[6][0], 0, 0, 0);
    acc[6][1] = __builtin_amdgcn_mfma_f32_16x16x32_bf16(a2, bg1, acc[6][1], 0, 0, 0);
    acc[6][2] = __builtin_amdgcn_mfma_f32_16x16x32_bf16(a2, bg2, acc[6][2], 0, 0, 0);
    acc[6][3] = __builtin_amdgcn_mfma_f32_16x16x32_bf16(a2, bg3, acc[6][3], 0, 0, 0);
    acc[7][0] = __builtin_amdgcn_mfma_f32_16x16x32_bf16(a3, bg0, acc[7][0], 0, 0, 0);
    acc[7][1] = __builtin_amdgcn_mfma_f32_16x16x32_bf16(a3, bg1, acc[7][1], 0, 0, 0);
    acc[7][2] = __builtin_amdgcn_mfma_f32_16x16x32_bf16(a3, bg2, acc[7][2], 0, 0, 0);
    acc[7][3] = __builtin_amdgcn_mfma_f32_16x16x32_bf16(a3, bg3, acc[7][3], 0, 0, 0);
    __builtin_amdgcn_s_setprio(0);
    __builtin_amdgcn_sched_barrier(0);
    __builtin_amdgcn_s_barrier();

    // ---- P2: af(m0-3,kk1)+bg(kk1); stage A(g0+4)
    a0 = *reinterpret_cast<const bf16x8*>(As1 + offA[0]);
    a1 = *reinterpret_cast<const bf16x8*>(As1 + offA[1]);
    a2 = *reinterpret_cast<const bf16x8*>(As1 + offA[2]);
    a3 = *reinterpret_cast<const bf16x8*>(As1 + offA[3]);
    bg0 = *reinterpret_cast<const bf16x8*>(Bs1 + offB[0]);
    bg1 = *reinterpret_cast<const bf16x8*>(Bs1 + offB[1]);
    bg2 = *reinterpret_cast<const bf16x8*>(Bs1 + offB[2]);
    bg3 = *reinterpret_cast<const bf16x8*>(Bs1 + offB[3]);
    STAGE_A(g0 + 4);
    __builtin_amdgcn_sched_barrier(0);
    __builtin_amdgcn_s_barrier();
    asm volatile("s_waitcnt lgkmcnt(0)" ::: "memory");
    __builtin_amdgcn_sched_barrier(0);
    __builtin_amdgcn_s_setprio(1);
    acc[0][0] = __builtin_amdgcn_mfma_f32_16x16x32_bf16(a0, bg0, acc[0][0], 0, 0, 0);
    acc[0][1] = __builtin_amdgcn_mfma_f32_16x16x32_bf16(a0, bg1, acc[0][1], 0, 0, 0);
    acc[0][2] = __builtin_amdgcn_mfma_f32_16x16x32_bf16(a0, bg2, acc[0][2], 0, 0, 0);
    acc[0][3] = __builtin_amdgcn_mfma_f32_16x16x32_bf16(a0, bg3, acc[0][3], 0, 0, 0);
    acc[1][0] = __builtin_amdgcn_mfma_f32_16x16x32_bf16(a1, bg0, acc[1][0], 0, 0, 0);
    acc[1][1] = __builtin_amdgcn_mfma_f32_16x16x32_bf16(a1, bg1, acc[1][1], 0, 0, 0);
    acc[1][2] = __builtin_amdgcn_mfma_f32_16x16x32_bf16(a1, bg2, acc[1][2], 0, 0, 0);
    acc[1][3] = __builtin_amdgcn_mfma_f32_16x16x32_bf16(a1, bg3, acc[1][3], 0, 0, 0);
    acc[2][0] = __builtin_amdgcn_mfma_f32_16x16x32_bf16(a2, bg0, acc[2][0], 0, 0, 0);
    acc[2][1] = __builtin_amdgcn_mfma_f32_16x16x32_bf16(a2, bg1, acc[2][1], 0, 0, 0);
    acc[2][2] = __builtin_amdgcn_mfma_f32_16x16x32_bf16(a2, bg2, acc[2][2], 0, 0, 0);
    acc[2][3] = __builtin_amdgcn_mfma_f32_16x16x32_bf16(a2, bg3, acc[2][3], 0, 0, 0);
    acc[3][0] = __builtin_amdgcn_mfma_f32_16x16x32_bf16(a3, bg0, acc[3][0], 0, 0, 0);
    acc[3][1] = __builtin_amdgcn_mfma_f32_16x16x32_bf16(a3, bg1, acc[3][1], 0, 0, 0);
    acc[3][2] = __builtin_amdgcn_mfma_f32_16x16x32_bf16(a3, bg2, acc[3][2], 0, 0, 0);
    acc[3][3] = __builtin_amdgcn_mfma_f32_16x16x32_bf16(a3, bg3, acc[3][3], 0, 0, 0);
    __builtin_amdgcn_s_setprio(0);
    __builtin_amdgcn_sched_barrier(0);
    __builtin_amdgcn_s_barrier();

    // ---- P3: af(m4-7,kk1); stage B(g0+5); single per-tile vmcnt(6)
    a0 = *reinterpret_cast<const bf16x8*>(As1 + offA[4]);
    a1 = *reinterpret_cast<const bf16x8*>(As1 + offA[5]);
    a2 = *reinterpret_cast<const bf16x8*>(As1 + offA[6]);
    a3 = *reinterpret_cast<const bf16x8*>(As1 + offA[7]);
    STAGE_B(g0 + 5);
    __builtin_amdgcn_sched_barrier(0);
    __builtin_amdgcn_s_barrier();
    asm volatile("s_waitcnt lgkmcnt(0)" ::: "memory");
    __builtin_amdgcn_sched_barrier(0);
    __builtin_amdgcn_s_setprio(1);
    acc[4][0] = __builtin_amdgcn_mfma_f32_16x16x32_bf16(a0, bg0, acc[4][0], 0, 0, 0);
    acc[4][1] = __builtin_amdgcn_mfma_f32_16x16x32_bf16(a0, bg1, acc[4][1], 0, 0, 0);
    acc[4][2] = __builtin_amdgcn_mfma_f32_16x16x32_bf16(a0, bg2, acc[4][2], 0, 0, 0);
    acc[4][3] = __builtin_amdgcn_mfma_f32_16x16x32_bf16(a0, bg3, acc[4][3], 0, 0, 0);
    acc[5][0] = __builtin_amdgcn_mfma_f32_16x16x32_bf16(a1, bg0, acc[5][0], 0, 0, 0);
    acc[5][1] = __builtin_amdgcn_mfma_f32_16x16x32_bf16(a1, bg1, acc[5][1], 0, 0, 0);
    acc[5][2] = __builtin_amdgcn_mfma_f32_16x16x32_bf16(a1, bg2, acc[5][2], 0, 0, 0);
    acc[5][3] = __builtin_amdgcn_mfma_f32_16x16x32_bf16(a1, bg3, acc[5][3], 0, 0, 0);
    acc[6][0] = __builtin_amdgcn_mfma_f32_16x16x32_bf16(a2, bg0, acc[6][0], 0, 0, 0);
    acc[6][1] = __builtin_amdgcn_mfma_f32_16x16x32_bf16(a2, bg1, acc[6][1], 0, 0, 0);
    acc[6][2] = __builtin_amdgcn_mfma_f32_16x16x32_bf16(a2, bg2, acc[6][2], 0, 0, 0);
    acc[6][3] = __builtin_amdgcn_mfma_f32_16x16x32_bf16(a2, bg3, acc[6][3], 0, 0, 0);
    acc[7][0] = __builtin_amdgcn_mfma_f32_16x16x32_bf16(a3, bg0, acc[7][0], 0, 0, 0);
    acc[7][1] = __builtin_amdgcn_mfma_f32_16x16x32_bf16(a3, bg1, acc[7][1], 0, 0, 0);
    acc[7][2] = __builtin_amdgcn_mfma_f32_16x16x32_bf16(a3, bg2, acc[7][2], 0, 0, 0);
    acc[7][3] = __builtin_amdgcn_mfma_f32_16x16x32_bf16(a3, bg3, acc[7][3], 0, 0, 0);
    __builtin_amdgcn_s_setprio(0);
    __builtin_amdgcn_sched_barrier(0);
    asm volatile("s_waitcnt vmcnt(6)" ::: "memory");
    __builtin_amdgcn_s_barrier();
  }

  if (kunits & 1) {
    asm volatile("s_waitcnt vmcnt(0)" ::: "memory");
    __builtin_amdgcn_s_barrier();
    const int g = kunits - 1;
    const u16* As = lds + ((g & 3) * 8192);
    const u16* Bs = lds + 32768 + ((g & 3) * 8192);
    bg0 = *reinterpret_cast<const bf16x8*>(Bs + offB[0]);
    bg1 = *reinterpret_cast<const bf16x8*>(Bs + offB[1]);
    bg2 = *reinterpret_cast<const bf16x8*>(Bs + offB[2]);
    bg3 = *reinterpret_cast<const bf16x8*>(Bs + offB[3]);
    #pragma unroll
    for (int m = 0; m < 8; ++m) {
      bf16x8 am = *reinterpret_cast<const bf16x8*>(As + offA[m]);
      acc[m][0] = __builtin_amdgcn_mfma_f32_16x16x32_bf16(am, bg0, acc[m][0], 0, 0, 0);
      acc[m][1] = __builtin_amdgcn_mfma_f32_16x16x32_bf16(am, bg1, acc[m][1], 0, 0, 0);
      acc[m][2] = __builtin_amdgcn_mfma_f32_16x16x32_bf16(am, bg2, acc[m][2], 0, 0, 0);
      acc[m][3] = __builtin_amdgcn_mfma_f32_16x16x32_bf16(am, bg3, acc[m][3], 0, 0, 0);
    }
  }
#undef STAGE_A
#undef STAGE_B

  float* C = Cp + (size_t)sb * M * N;
  #pragma unroll
  for (int m = 0; m < 8; ++m) {
    const int rb = mb * 256 + wm * 128 + m * 16 + (lane >> 4) * 4;
    #pragma unroll
    for (int n = 0; n < 4; ++n) {
      const int col = nb * 256 + wn * 64 + n * 16 + (lane & 15);
      #pragma unroll
      for (int j2 = 0; j2 < 4; ++j2)
        __builtin_nontemporal_store(acc[m][n][j2], &C[(size_t)(rb + j2) * N + col]);
    }
  }
}

// ---------------------------------------------------------------------------
// 128x128 m97-structure GEMM for the small layers 2/3
// ---------------------------------------------------------------------------
__global__ __launch_bounds__(256) void gemm_bf16(
    const u16* __restrict__ A, const u16* __restrict__ Bt,
    float* __restrict__ Cp, int M, int N, int K, int kps)
{
  __shared__ __align__(16) u16 lA[128 * 32];
  __shared__ __align__(16) u16 lB[128 * 32];
  const int tid = threadIdx.x;
  const int mb = blockIdx.x, nb = blockIdx.y, sb = blockIdx.z;
  const int w = tid >> 6, lane = tid & 63;
  const int wr = (w >> 1) * 64, wc = (w & 1) * 64;
  const int lrow = lane & 15, lko = (lane >> 4) * 8;

  f32x4 acc[4][4];
  #pragma unroll
  for (int m = 0; m < 4; ++m)
    #pragma unroll
    for (int n = 0; n < 4; ++n) acc[m][n] = f32x4{0.f, 0.f, 0.f, 0.f};

  const u16* Ab = A + (size_t)mb * 128 * K;
  const u16* Bb = Bt + (size_t)nb * 128 * K;
  const int r0 = tid >> 2, inn = (tid & 3) * 8;
  const int l0 = (tid & ~63) * 8, l1 = ((256 + tid) & ~63) * 8;

  const int ks1 = (sb + 1) * kps;
  for (int ks = sb * kps; ks < ks1; ++ks) {
    const int k0 = ks * 32;
    __syncthreads();
    gload16(Ab + (size_t)r0 * K + k0 + inn,        lA + l0);
    gload16(Ab + (size_t)(r0 + 64) * K + k0 + inn, lA + l1);
    gload16(Bb + (size_t)r0 * K + k0 + inn,        lB + l0);
    gload16(Bb + (size_t)(r0 + 64) * K + k0 + inn, lB + l1);
    __syncthreads();
    bf16x8 af[4], bg[4];
    #pragma unroll
    for (int m = 0; m < 4; ++m)
      af[m] = *reinterpret_cast<const bf16x8*>(&lA[(wr + m * 16 + lrow) * 32 + lko]);
    #pragma unroll
    for (int n = 0; n < 4; ++n)
      bg[n] = *reinterpret_cast<const bf16x8*>(&lB[(wc + n * 16 + lrow) * 32 + lko]);
    #pragma unroll
    for (int m = 0; m < 4; ++m)
      #pragma unroll
      for (int n = 0; n < 4; ++n)
        acc[m][n] = __builtin_amdgcn_mfma_f32_16x16x32_bf16(af[m], bg[n], acc[m][n], 0, 0, 0);
  }

  float* C = Cp + (size_t)sb * M * N;
  #pragma unroll
  for (int m = 0; m < 4; ++m) {
    const int rb = mb * 128 + wr + m * 16 + (lane >> 4) * 4;
    #pragma unroll
    for (int n = 0; n < 4; ++n) {
      const int col = nb * 128 + wc + n * 16 + (lane & 15);
      #pragma unroll
      for (int j = 0; j < 4; ++j)
        __builtin_nontemporal_store(acc[m][n][j], &C[(size_t)(rb + j) * N + col]);
    }
  }
}

// ---------------------------------------------------------------------------
// Split-K reduce + bias + relu -> bf16 (layers 1/2), vectorized
// ---------------------------------------------------------------------------
__global__ __launch_bounds__(256) void reduce_bias_relu_bf16(
    const float* __restrict__ part, int S, size_t MN,
    const float* __restrict__ bias, int nmask, u16* __restrict__ out)
{
  const size_t n8 = MN >> 3;
  for (size_t i8 = blockIdx.x * 256ull + threadIdx.x; i8 < n8; i8 += (size_t)gridDim.x * 256) {
    const size_t base = i8 * 8;
    f32x4 lo = {0.f, 0.f, 0.f, 0.f}, hi = {0.f, 0.f, 0.f, 0.f};
    for (int k = 0; k < S; ++k) {
      const float* p = part + (size_t)k * MN + base;
      f32x4 a = __builtin_nontemporal_load(reinterpret_cast<const f32x4*>(p));
      f32x4 b = __builtin_nontemporal_load(reinterpret_cast<const f32x4*>(p + 4));
      lo += a; hi += b;
    }
    const int bb = (int)(base & (size_t)nmask);
    const f32x4 b0 = *reinterpret_cast<const f32x4*>(bias + bb);
    const f32x4 b1 = *reinterpret_cast<const f32x4*>(bias + bb + 4);
    u16x8 v;
    #pragma unroll
    for (int e = 0; e < 4; ++e) v[e] = f2bf(fmaxf(lo[e] + b0[e], 0.f));
    #pragma unroll
    for (int e = 0; e < 4; ++e) v[4 + e] = f2bf(fmaxf(hi[e] + b1[e], 0.f));
    *reinterpret_cast<u16x8*>(out + base) = v;
  }
}

// ---------------------------------------------------------------------------
// Merged layer-3 reduce + bias + relu + final dot: out[b] = relu(sum4+b3).Wout + bout
// One wave per row; identical FP order to the former reduce_f32 + final_dot.
// ---------------------------------------------------------------------------
__global__ __launch_bounds__(256) void reduce3_final(
    const float* __restrict__ part, const float* __restrict__ bd3,
    const float* __restrict__ Wout, const float* __restrict__ bout,
    float* __restrict__ out)
{
  const int row = blockIdx.x * 4 + (threadIdx.x >> 6);
  const int lane = threadIdx.x & 63;
  const size_t MN = (size_t)BATCH * HD3;
  const size_t base = (size_t)row * HD3;
  float s = 0.f;
  #pragma unroll
  for (int i = 0; i < 4; ++i) {
    const int e = lane + i * 64;
    float v = 0.f;
    #pragma unroll
    for (int k = 0; k < 4; ++k)
      v += __builtin_nontemporal_load(&part[(size_t)k * MN + base + e]);
    v = fmaxf(v + bd3[e], 0.f);
    s += v * Wout[e];
  }
  #pragma unroll
  for (int off = 32; off; off >>= 1) s += __shfl_down(s, off, 64);
  if (lane == 0) out[row] = s + bout[0];
}

// ---------------------------------------------------------------------------
extern "C" void kernel_launch(void* const* d_in, const int* in_sizes, int n_in,
                              void* d_out, int out_size, void* d_ws, size_t ws_size,
                              hipStream_t stream)
{
  const int*   cat    = (const int*)  d_in[0];
  const float* num    = (const float*)d_in[1];
  const float* tables = (const float*)d_in[2];
  const float* nemb   = (const float*)d_in[3];
  const float* Wse1   = (const float*)d_in[4];
  const float* Wse2   = (const float*)d_in[5];
  const float* Wbil   = (const float*)d_in[6];
  const float* Wd1    = (const float*)d_in[7];
  const float* bd1    = (const float*)d_in[8];
  const float* Wd2    = (const float*)d_in[9];
  const float* bd2    = (const float*)d_in[10];
  const float* Wd3    = (const float*)d_in[11];
  const float* bd3    = (const float*)d_in[12];
  const float* Wout   = (const float*)d_in[13];
  const float* bout   = (const float*)d_in[14];

  char* ws = (char*)d_ws;
  // ws layout (total 311,230,464 B — round-3 proven footprint):
  u16*   hid  = (u16*)  (ws + 0ull);           // 194,248,704  bf16 [4096][23712]
  u16*   W1t  = (u16*)  (ws + 194248704ull);   //  48,562,176  bf16 [1024][23712]
  float* part = (float*)(ws + 242810880ull);   //  67,108,864  f32 splitK partials (S<=4)
  u16*   W2t  = (u16*)  (ws + 309919744ull);   //   1,048,576  bf16 [512][1024]
  u16*   W3t  = (u16*)  (ws + 310968320ull);   //     262,144  bf16 [256][512]
  // dead-hid region reuse (hid consumed by gemm1 before these are written):
  u16*   h1b  = (u16*)  (ws + 0ull);           //   8,388,608  bf16 [4096][1024]
  u16*   h2b  = (u16*)  (ws + 8388608ull);     //   4,194,304  bf16 [4096][512]

  transpose_all<<<741 * 32 + 512 + 128, 256, 0, stream>>>(Wd1, Wd2, Wd3, W1t, W2t, W3t);
  fuse_front<<<BATCH / 2, 256, 0, stream>>>(cat, num, tables, nemb, Wse1, Wse2, Wbil, hid);

  // layer 1: [4096 x 23712] @ [23712 x 1024], 256^2 fine-phase pipelined,
  // split-K=4 uneven (186/186/186/183 units of 32), 1D grid 256 = exact CU fill
  gemm8p_bf16<<<256, 512, 0, stream>>>(hid, W1t, part, BATCH, HD1, KHID, 741, 186);
  reduce_bias_relu_bf16<<<2048, 256, 0, stream>>>(part, 4, (size_t)BATCH * HD1, bd1, HD1 - 1, h1b);

  // layer 2: [4096 x 1024] @ [1024 x 512], split-K=2 (32 = 2*16)
  gemm_bf16<<<dim3(BATCH / 128, HD2 / 128, 2), 256, 0, stream>>>(h1b, W2t, part, BATCH, HD2, HD1, 16);
  reduce_bias_relu_bf16<<<1024, 256, 0, stream>>>(part, 2, (size_t)BATCH * HD2, bd2, HD2 - 1, h2b);

  // layer 3: [4096 x 512] @ [512 x 256], split-K=4 (16 = 4*4)
  gemm_bf16<<<dim3(BATCH / 128, HD3 / 128, 4), 256, 0, stream>>>(h2b, W3t, part, BATCH, HD3, HD2, 4);
  reduce3_final<<<BATCH / 4, 256, 0, stream>>>(part, bd3, Wout, bout, (float*)d_out);
}